// Round 4
// baseline (3035.660 us; speedup 1.0000x reference)
//
#include <hip/hip_runtime.h>

#define NN 10000
#define NE 160000
#define NG 16
#define NFD 64
#define EFD 32
#define H 256
#define OUTD 512
#define NL 3

typedef short v8s __attribute__((ext_vector_type(8)));
typedef float v4f __attribute__((ext_vector_type(4)));

__device__ __forceinline__ unsigned short f2bf(float f){
  unsigned int u = __float_as_uint(f);
  u = u + 0x7fffu + ((u >> 16) & 1u);
  return (unsigned short)(u >> 16);
}

// block = 256 threads (4 waves); reduces a and b (sum) across the block
__device__ __forceinline__ void blockReduce2(float& a, float& b, volatile float* scr){
  #pragma unroll
  for (int o = 32; o > 0; o >>= 1){
    a += __shfl_down(a, o);
    b += __shfl_down(b, o);
  }
  int lane = threadIdx.x & 63, w = threadIdx.x >> 6;
  __syncthreads();
  if (lane == 0){ scr[w] = a; scr[4 + w] = b; }
  __syncthreads();
  a = scr[0] + scr[1] + scr[2] + scr[3];
  b = scr[4] + scr[5] + scr[6] + scr[7];
}

// ---------------- node encoder: x = relu(LN(nf @ W + b)) ----------------
__global__ void node_enc(const float* __restrict__ nf, const float* __restrict__ W,
                         const float* __restrict__ b, const float* __restrict__ g,
                         const float* __restrict__ be,
                         float* __restrict__ x, unsigned short* __restrict__ xb){
  __shared__ float nfs[4][NFD];
  __shared__ float scr[8];
  int tid = threadIdx.x;
  int n0 = blockIdx.x * 4;
  { int n = tid >> 6, k = tid & 63; nfs[n][k] = nf[(n0 + n) * NFD + k]; }
  __syncthreads();
  float acc[4];
  #pragma unroll
  for (int n = 0; n < 4; n++) acc[n] = b[tid];
  for (int k = 0; k < NFD; k++){
    float w = W[k * H + tid];
    #pragma unroll
    for (int n = 0; n < 4; n++) acc[n] += nfs[n][k] * w;
  }
  for (int n = 0; n < 4; n++){
    float s1 = acc[n], s2 = acc[n] * acc[n];
    blockReduce2(s1, s2, scr);
    float m = s1 / H, va = s2 / H - m * m;
    float y = (acc[n] - m) * rsqrtf(va + 1e-5f) * g[tid] + be[tid];
    y = fmaxf(y, 0.f);
    x[(size_t)(n0 + n) * H + tid] = y;
    xb[(size_t)(n0 + n) * H + tid] = f2bf(y);
  }
}

// ---------------- edge encoder: edge_attr = relu(LN(ef @ W + b)) (bf16 out) ----
__global__ void edge_enc(const float* __restrict__ ef, const float* __restrict__ W,
                         const float* __restrict__ b, const float* __restrict__ g,
                         const float* __restrict__ be, unsigned short* __restrict__ eab){
  __shared__ float efs[8][EFD];
  __shared__ float scr[8];
  int tid = threadIdx.x;
  int e0 = blockIdx.x * 8;
  { int n = tid >> 5, k = tid & 31; efs[n][k] = ef[(e0 + n) * EFD + k]; }
  __syncthreads();
  float acc[8];
  #pragma unroll
  for (int n = 0; n < 8; n++) acc[n] = b[tid];
  for (int k = 0; k < EFD; k++){
    float w = W[k * H + tid];
    #pragma unroll
    for (int n = 0; n < 8; n++) acc[n] += efs[n][k] * w;
  }
  for (int n = 0; n < 8; n++){
    float s1 = acc[n], s2 = acc[n] * acc[n];
    blockReduce2(s1, s2, scr);
    float m = s1 / H, va = s2 / H - m * m;
    float y = (acc[n] - m) * rsqrtf(va + 1e-5f) * g[tid] + be[tid];
    y = fmaxf(y, 0.f);
    eab[(size_t)(e0 + n) * H + tid] = f2bf(y);
  }
}

// ---------------- degree ----------------
__global__ void deg_kernel(const int* __restrict__ dst, float* __restrict__ deg){
  int e = blockIdx.x * 256 + threadIdx.x;
  if (e < NE) unsafeAtomicAdd(&deg[dst[e]], 1.0f);
}

// ---------------- weight packing into MFMA fragment order ----------------
// w1p[l][kb(24)][cb(16)][lane(64)][i(8)] = w1[l][kb*32+8*(lane>>4)+i][cb*16+(lane&15)]
__global__ void pack_w1(const float* __restrict__ w1, unsigned short* __restrict__ w1p){
  int b = blockIdx.x;            // l*384 + kb*16 + cb  (3*24*16 = 1152)
  int lane = threadIdx.x;
  int l = b / 384; int rem = b % 384; int kb = rem >> 4; int cb = rem & 15;
  const float* W = w1 + (size_t)l * 768 * H;
  unsigned short* out = w1p + ((size_t)b * 64 + lane) * 8;
  int col = cb * 16 + (lane & 15);
  int k0 = kb * 32 + 8 * (lane >> 4);
  #pragma unroll
  for (int i = 0; i < 8; i++) out[i] = f2bf(W[(size_t)(k0 + i) * H + col]);
}

// w2tp[l][hb(16)][kb(8)][lane(64)][i(8)] = w2[l][kb*32+8*(lane>>4)+i][hb*16+(lane&15)]
__global__ void pack_w2t(const float* __restrict__ w2, unsigned short* __restrict__ w2tp){
  int b = blockIdx.x;            // l*128 + hb*8 + kb  (3*16*8 = 384)
  int lane = threadIdx.x;
  int l = b / 128; int rem = b % 128; int hb = rem >> 3; int kb = rem & 7;
  const float* W = w2 + (size_t)l * H * H;
  unsigned short* out = w2tp + ((size_t)b * 64 + lane) * 8;
  int row = hb * 16 + (lane & 15);   // output col of C2
  int k0 = kb * 32 + 8 * (lane >> 4);
  #pragma unroll
  for (int i = 0; i < 8; i++) out[i] = f2bf(W[(size_t)(k0 + i) * H + row]);
}

// ---------------- fused edge MLP (GEMM1 + relu + GEMM2 + scatter) ----------------
// 64 edges / block, 4 waves. GEMM1: C1[64,256] = relu(A[64,768] @ W1 + b1)
// GEMM2: C2^T[256,64] = W2^T @ C1^T ; scatter-add (+b2) into agg[dst].
__launch_bounds__(256)
__global__ void edge_mlp(const unsigned short* __restrict__ xb,
                         const unsigned short* __restrict__ eab,
                         const int* __restrict__ src, const int* __restrict__ dst,
                         const unsigned short* __restrict__ w1p,
                         const float* __restrict__ b1,
                         const unsigned short* __restrict__ w2tp,
                         const float* __restrict__ b2,
                         float* __restrict__ agg){
  __shared__ unsigned short As[64 * 64];     // K-tile staging, XOR-swizzled (8 KB)
  __shared__ unsigned short C1s[64 * 256];   // C1 bf16, XOR-swizzled (32 KB)
  __shared__ int srcs[64], dsts[64];
  int tid = threadIdx.x;
  int e0 = blockIdx.x * 64;
  if (tid < 64){ srcs[tid] = src[e0 + tid]; dsts[tid] = dst[e0 + tid]; }
  int wave = tid >> 6, lane = tid & 63;
  int rl = lane & 15, q = lane >> 4;
  v4f acc[4][4];
  #pragma unroll
  for (int i = 0; i < 4; i++)
    #pragma unroll
    for (int j = 0; j < 4; j++) acc[i][j] = (v4f){0.f, 0.f, 0.f, 0.f};

  for (int kt = 0; kt < 12; ++kt){
    int seg = kt >> 2, off = (kt & 3) * 64;
    __syncthreads();
    #pragma unroll
    for (int h = 0; h < 2; ++h){
      int c = tid + h * 256;          // 512 chunks of 16B: edge = c>>3, chunk = c&7
      int e = c >> 3, ck = c & 7;
      const unsigned short* p;
      if (seg == 0)      p = xb + (size_t)srcs[e] * H;
      else if (seg == 1) p = xb + (size_t)dsts[e] * H;
      else               p = eab + (size_t)(e0 + e) * H;
      int4 v = *(const int4*)(p + off + ck * 8);
      *(int4*)&As[e * 64 + ((ck ^ (e & 7)) << 3)] = v;
    }
    __syncthreads();
    #pragma unroll
    for (int k2 = 0; k2 < 2; k2++){
      int kb = kt * 2 + k2;           // global k-block (0..23)
      v8s af[4];
      #pragma unroll
      for (int rb = 0; rb < 4; rb++){
        int row = rb * 16 + rl;
        int ck = k2 * 4 + q;
        af[rb] = *(const v8s*)&As[row * 64 + ((ck ^ (row & 7)) << 3)];
      }
      #pragma unroll
      for (int cb = 0; cb < 4; cb++){
        v8s bf = *(const v8s*)&w1p[(((size_t)kb * 16 + (wave * 4 + cb)) * 64 + lane) * 8];
        #pragma unroll
        for (int rb = 0; rb < 4; rb++)
          acc[rb][cb] = __builtin_amdgcn_mfma_f32_16x16x32_bf16(af[rb], bf, acc[rb][cb], 0, 0, 0);
      }
    }
  }
  // GEMM1 epilogue: bias + relu -> bf16 -> swizzled LDS (row-major [edge][hidden])
  #pragma unroll
  for (int rb = 0; rb < 4; rb++){
    #pragma unroll
    for (int cb = 0; cb < 4; cb++){
      int col = wave * 64 + cb * 16 + rl;
      float bb = b1[col];
      #pragma unroll
      for (int j = 0; j < 4; j++){
        int row = rb * 16 + q * 4 + j;
        float v = fmaxf(acc[rb][cb][j] + bb, 0.f);
        C1s[row * 256 + (((col >> 3) ^ (row & 7)) << 3) + (col & 7)] = f2bf(v);
      }
    }
  }
  __syncthreads();
  // GEMM2: D = W2^T @ C1^T, wave owns output-cols [64w, 64w+64)
  v4f acc2[4][4];
  #pragma unroll
  for (int i = 0; i < 4; i++)
    #pragma unroll
    for (int j = 0; j < 4; j++) acc2[i][j] = (v4f){0.f, 0.f, 0.f, 0.f};
  #pragma unroll
  for (int kb = 0; kb < 8; kb++){
    v8s af[4];
    #pragma unroll
    for (int rb = 0; rb < 4; rb++)
      af[rb] = *(const v8s*)&w2tp[(((size_t)(wave * 4 + rb) * 8 + kb) * 64 + lane) * 8];
    #pragma unroll
    for (int cb = 0; cb < 4; cb++){
      int row = cb * 16 + rl;         // edge row in C1s
      int ck = kb * 4 + q;
      v8s bf = *(const v8s*)&C1s[row * 256 + ((ck ^ (row & 7)) << 3)];
      #pragma unroll
      for (int rb = 0; rb < 4; rb++)
        acc2[rb][cb] = __builtin_amdgcn_mfma_f32_16x16x32_bf16(af[rb], bf, acc2[rb][cb], 0, 0, 0);
    }
  }
  // scatter: D[row=out-col][col=edge] += b2; atomicAdd into agg[dst[e]]
  #pragma unroll
  for (int cb = 0; cb < 4; cb++){
    int e = cb * 16 + rl;
    float* arow = agg + (size_t)dsts[e] * H;
    #pragma unroll
    for (int rb = 0; rb < 4; rb++){
      int oc0 = wave * 64 + rb * 16 + q * 4;
      #pragma unroll
      for (int j = 0; j < 4; j++)
        unsafeAtomicAdd(&arow[oc0 + j], acc2[rb][cb][j] + b2[oc0 + j]);
    }
  }
}

// ---------------- fused GRU + LayerNorm (8 nodes / block) ----------------
__global__ void gru_kernel(const float* __restrict__ agg, const float* __restrict__ deg,
                           float* __restrict__ x, unsigned short* __restrict__ xb,
                           const float* __restrict__ wih, const float* __restrict__ whh,
                           const float* __restrict__ bih, const float* __restrict__ bhh,
                           const float* __restrict__ lng, const float* __restrict__ lnb){
  __shared__ float aggs[8][H];
  __shared__ float xs[8][H];
  __shared__ float hs[8][H];
  __shared__ float scr[8];
  __shared__ float invd[8];
  __shared__ float dg[8];
  int tid = threadIdx.x;
  int n0 = blockIdx.x * 8;
  if (tid < 8){ float d = deg[n0 + tid]; dg[tid] = d; invd[tid] = 1.f / fmaxf(d, 1.f); }
  __syncthreads();
  for (int idx = tid; idx < 8 * H; idx += 256){
    int n = idx >> 8, k = idx & 255;
    aggs[n][k] = agg[(size_t)(n0 + n) * H + k] * invd[n];
    xs[n][k]   = x[(size_t)(n0 + n) * H + k];
  }
  __syncthreads();
  float gr[8] = {0}, gz[8] = {0}, gn[8] = {0}, hr[8] = {0}, hz[8] = {0}, hn[8] = {0};
  for (int k = 0; k < H; k++){
    float wr = wih[k * 768 + tid], wz = wih[k * 768 + 256 + tid], wn = wih[k * 768 + 512 + tid];
    float ur = whh[k * 768 + tid], uz = whh[k * 768 + 256 + tid], un = whh[k * 768 + 512 + tid];
    #pragma unroll
    for (int n = 0; n < 8; n++){
      float a = aggs[n][k], xx = xs[n][k];
      gr[n] += a * wr;  gz[n] += a * wz;  gn[n] += a * wn;
      hr[n] += xx * ur; hz[n] += xx * uz; hn[n] += xx * un;
    }
  }
  float bir = bih[tid], biz = bih[256 + tid], bin = bih[512 + tid];
  float bhr = bhh[tid], bhz = bhh[256 + tid], bhn = bhh[512 + tid];
  #pragma unroll
  for (int n = 0; n < 8; n++){
    float r  = 1.f / (1.f + __expf(-(gr[n] + bir + hr[n] + bhr)));
    float z  = 1.f / (1.f + __expf(-(gz[n] + biz + hz[n] + bhz)));
    float ng = tanhf(gn[n] + bin + r * (hn[n] + bhn));
    float hnew = (1.f - z) * ng + z * xs[n][tid];
    hs[n][tid] = (dg[n] > 0.f) ? hnew : xs[n][tid];
  }
  __syncthreads();
  for (int n = 0; n < 8; n++){
    float v0 = hs[n][tid];
    float s1 = v0, s2 = v0 * v0;
    blockReduce2(s1, s2, scr);
    float m = s1 / H, va = s2 / H - m * m;
    float y = (v0 - m) * rsqrtf(va + 1e-5f) * lng[tid] + lnb[tid];
    x[(size_t)(n0 + n) * H + tid] = y;
    xb[(size_t)(n0 + n) * H + tid] = f2bf(y);
  }
}

// ---------------- attention scores ----------------
__global__ void scores_kernel(const float* __restrict__ x, const float* __restrict__ w1,
                              const float* __restrict__ b1, const float* __restrict__ w2,
                              const float* __restrict__ b2, float* __restrict__ s){
  __shared__ float xs[4][H];
  __shared__ float scr[8];
  int tid = threadIdx.x;
  int n0 = blockIdx.x * 4;
  for (int idx = tid; idx < 4 * H; idx += 256){
    int n = idx >> 8, k = idx & 255;
    xs[n][k] = x[(size_t)(n0 + n) * H + k];
  }
  __syncthreads();
  float acc[4];
  #pragma unroll
  for (int n = 0; n < 4; n++) acc[n] = b1[tid];
  for (int k = 0; k < H; k++){
    float w = w1[k * H + tid];
    #pragma unroll
    for (int n = 0; n < 4; n++) acc[n] += xs[n][k] * w;
  }
  float w2v = w2[tid];
  for (int n = 0; n < 4; n++){
    float s1 = tanhf(acc[n]) * w2v, s2 = 0.f;
    blockReduce2(s1, s2, scr);
    if (tid == 0) s[n0 + n] = s1 + b2[0];
  }
}

// ---------------- per-graph softmax pooling (16 blocks) ----------------
__global__ void pool_kernel(const float* __restrict__ x, const float* __restrict__ s,
                            const int* __restrict__ batch, float* __restrict__ pooled){
  __shared__ float scr[8];
  int g = blockIdx.x, tid = threadIdx.x;
  // boundaries in sorted batch
  int a = 0, b = NN;
  while (a < b){ int mid = (a + b) >> 1; if (batch[mid] < g) a = mid + 1; else b = mid; }
  int lo = a;
  a = lo; b = NN;
  while (a < b){ int mid = (a + b) >> 1; if (batch[mid] < g + 1) a = mid + 1; else b = mid; }
  int hi = a;
  // max
  float mx = -3.4e38f;
  for (int i = lo + tid; i < hi; i += 256) mx = fmaxf(mx, s[i]);
  #pragma unroll
  for (int o = 32; o > 0; o >>= 1) mx = fmaxf(mx, __shfl_down(mx, o));
  int lane = tid & 63, w = tid >> 6;
  __syncthreads();
  if (lane == 0) scr[w] = mx;
  __syncthreads();
  mx = fmaxf(fmaxf(scr[0], scr[1]), fmaxf(scr[2], scr[3]));
  // denom
  float den = 0.f;
  for (int i = lo + tid; i < hi; i += 256) den += __expf(s[i] - mx);
  float d2 = 0.f;
  blockReduce2(den, d2, scr);
  // weighted sum; thread owns column tid
  float pj = 0.f;
  for (int i = lo; i < hi; i++){
    float wgt = __expf(s[i] - mx);
    pj += wgt * x[(size_t)i * H + tid];
  }
  pooled[g * H + tid] = pj / den;
}

// ---------------- final projection + LN ----------------
__global__ void proj_kernel(const float* __restrict__ pooled, const float* __restrict__ W,
                            const float* __restrict__ b, const float* __restrict__ g,
                            const float* __restrict__ be, float* __restrict__ out){
  __shared__ float ps[H];
  __shared__ float scr[8];
  int gi = blockIdx.x, tid = threadIdx.x;
  ps[tid] = pooled[gi * H + tid];
  __syncthreads();
  float a0 = b[tid], a1 = b[tid + 256];
  for (int k = 0; k < H; k++){
    float p = ps[k];
    a0 += p * W[k * OUTD + tid];
    a1 += p * W[k * OUTD + tid + 256];
  }
  float s1 = a0 + a1, s2 = a0 * a0 + a1 * a1;
  blockReduce2(s1, s2, scr);
  float m = s1 / OUTD, va = s2 / OUTD - m * m;
  float rs = rsqrtf(va + 1e-5f);
  out[gi * OUTD + tid]       = (a0 - m) * rs * g[tid] + be[tid];
  out[gi * OUTD + tid + 256] = (a1 - m) * rs * g[tid + 256] + be[tid + 256];
}

extern "C" void kernel_launch(void* const* d_in, const int* in_sizes, int n_in,
                              void* d_out, int out_size, void* d_ws, size_t ws_size,
                              hipStream_t stream){
  const float* nf        = (const float*)d_in[0];
  const int*   eidx      = (const int*)d_in[1];
  const float* ef        = (const float*)d_in[2];
  const int*   batch     = (const int*)d_in[3];
  const float* node_w    = (const float*)d_in[4];
  const float* node_b    = (const float*)d_in[5];
  const float* node_g    = (const float*)d_in[6];
  const float* node_beta = (const float*)d_in[7];
  const float* edge_w    = (const float*)d_in[8];
  const float* edge_b    = (const float*)d_in[9];
  const float* edge_g    = (const float*)d_in[10];
  const float* edge_beta = (const float*)d_in[11];
  const float* mp_w1     = (const float*)d_in[12];
  const float* mp_b1     = (const float*)d_in[13];
  const float* mp_w2     = (const float*)d_in[14];
  const float* mp_b2     = (const float*)d_in[15];
  const float* gru_wih   = (const float*)d_in[16];
  const float* gru_whh   = (const float*)d_in[17];
  const float* gru_bih   = (const float*)d_in[18];
  const float* gru_bhh   = (const float*)d_in[19];
  const float* mp_ln_g   = (const float*)d_in[20];
  const float* mp_ln_b   = (const float*)d_in[21];
  const float* att_w1    = (const float*)d_in[22];
  const float* att_b1    = (const float*)d_in[23];
  const float* att_w2    = (const float*)d_in[24];
  const float* att_b2    = (const float*)d_in[25];
  const float* proj_w    = (const float*)d_in[26];
  const float* proj_b    = (const float*)d_in[27];
  const float* proj_g    = (const float*)d_in[28];
  const float* proj_beta = (const float*)d_in[29];
  const int* src = eidx;
  const int* dst = eidx + NE;

  char* ws = (char*)d_ws;
  size_t off = 0;
  auto alloc = [&](size_t bytes) -> void* {
    void* p = ws + off;
    off += (bytes + 511) & ~(size_t)511;
    return p;
  };
  float*          x      = (float*)alloc((size_t)NN * H * 4);
  unsigned short* xb     = (unsigned short*)alloc((size_t)NN * H * 2);
  unsigned short* eab    = (unsigned short*)alloc((size_t)NE * H * 2);
  float*          agg    = (float*)alloc((size_t)NN * H * 4);
  float*          deg    = (float*)alloc((size_t)NN * 4);
  float*          s      = (float*)alloc((size_t)NN * 4);
  float*          pooled = (float*)alloc((size_t)NG * H * 4);
  unsigned short* w1p    = (unsigned short*)alloc((size_t)3 * 24 * 16 * 64 * 8 * 2);
  unsigned short* w2tp   = (unsigned short*)alloc((size_t)3 * 16 * 8 * 64 * 8 * 2);

  hipMemsetAsync(deg, 0, (size_t)NN * 4, stream);
  pack_w1<<<1152, 64, 0, stream>>>(mp_w1, w1p);
  pack_w2t<<<384, 64, 0, stream>>>(mp_w2, w2tp);
  node_enc<<<NN / 4, 256, 0, stream>>>(nf, node_w, node_b, node_g, node_beta, x, xb);
  edge_enc<<<NE / 8, 256, 0, stream>>>(ef, edge_w, edge_b, edge_g, edge_beta, eab);
  deg_kernel<<<(NE + 255) / 256, 256, 0, stream>>>(dst, deg);

  for (int l = 0; l < NL; l++){
    hipMemsetAsync(agg, 0, (size_t)NN * H * 4, stream);
    edge_mlp<<<NE / 64, 256, 0, stream>>>(xb, eab, src, dst,
        w1p + (size_t)l * 24 * 16 * 64 * 8, mp_b1 + l * H,
        w2tp + (size_t)l * 16 * 8 * 64 * 8, mp_b2 + l * H, agg);
    gru_kernel<<<NN / 8, 256, 0, stream>>>(agg, deg, x, xb,
        gru_wih + (size_t)l * H * 768, gru_whh + (size_t)l * H * 768,
        gru_bih + l * 768, gru_bhh + l * 768,
        mp_ln_g + l * H, mp_ln_b + l * H);
  }
  scores_kernel<<<NN / 4, 256, 0, stream>>>(x, att_w1, att_b1, att_w2, att_b2, s);
  pool_kernel<<<NG, 256, 0, stream>>>(x, s, batch, pooled);
  proj_kernel<<<NG, 256, 0, stream>>>(pooled, proj_w, proj_b, proj_g, proj_beta, (float*)d_out);
  (void)in_sizes; (void)n_in; (void)out_size; (void)ws_size;
}

// Round 5
// 1919.139 us; speedup vs baseline: 1.5818x; 1.5818x over previous
//
#include <hip/hip_runtime.h>

#define NN 10000
#define NE 160000
#define NG 16
#define NFD 64
#define EFD 32
#define H 256
#define OUTD 512
#define NL 3

typedef short v8s __attribute__((ext_vector_type(8)));
typedef float v4f __attribute__((ext_vector_type(4)));

__device__ __forceinline__ unsigned short f2bf(float f){
  unsigned int u = __float_as_uint(f);
  u = u + 0x7fffu + ((u >> 16) & 1u);
  return (unsigned short)(u >> 16);
}
__device__ __forceinline__ float bf2f(unsigned short u){
  return __uint_as_float(((unsigned int)u) << 16);
}

// block = 256 threads (4 waves); reduces a and b (sum) across the block
__device__ __forceinline__ void blockReduce2(float& a, float& b, volatile float* scr){
  #pragma unroll
  for (int o = 32; o > 0; o >>= 1){
    a += __shfl_down(a, o);
    b += __shfl_down(b, o);
  }
  int lane = threadIdx.x & 63, w = threadIdx.x >> 6;
  __syncthreads();
  if (lane == 0){ scr[w] = a; scr[4 + w] = b; }
  __syncthreads();
  a = scr[0] + scr[1] + scr[2] + scr[3];
  b = scr[4] + scr[5] + scr[6] + scr[7];
}

// ---------------- node encoder: x = relu(LN(nf @ W + b)) ----------------
__global__ void node_enc(const float* __restrict__ nf, const float* __restrict__ W,
                         const float* __restrict__ b, const float* __restrict__ g,
                         const float* __restrict__ be,
                         float* __restrict__ x, unsigned short* __restrict__ xb){
  __shared__ float nfs[4][NFD];
  __shared__ float scr[8];
  int tid = threadIdx.x;
  int n0 = blockIdx.x * 4;
  { int n = tid >> 6, k = tid & 63; nfs[n][k] = nf[(n0 + n) * NFD + k]; }
  __syncthreads();
  float acc[4];
  #pragma unroll
  for (int n = 0; n < 4; n++) acc[n] = b[tid];
  for (int k = 0; k < NFD; k++){
    float w = W[k * H + tid];
    #pragma unroll
    for (int n = 0; n < 4; n++) acc[n] += nfs[n][k] * w;
  }
  for (int n = 0; n < 4; n++){
    float s1 = acc[n], s2 = acc[n] * acc[n];
    blockReduce2(s1, s2, scr);
    float m = s1 / H, va = s2 / H - m * m;
    float y = (acc[n] - m) * rsqrtf(va + 1e-5f) * g[tid] + be[tid];
    y = fmaxf(y, 0.f);
    x[(size_t)(n0 + n) * H + tid] = y;
    xb[(size_t)(n0 + n) * H + tid] = f2bf(y);
  }
}

// ---------------- edge encoder: edge_attr = relu(LN(ef @ W + b)) (bf16 out) ----
__global__ void edge_enc(const float* __restrict__ ef, const float* __restrict__ W,
                         const float* __restrict__ b, const float* __restrict__ g,
                         const float* __restrict__ be, unsigned short* __restrict__ eab){
  __shared__ float efs[8][EFD];
  __shared__ float scr[8];
  int tid = threadIdx.x;
  int e0 = blockIdx.x * 8;
  { int n = tid >> 5, k = tid & 31; efs[n][k] = ef[(e0 + n) * EFD + k]; }
  __syncthreads();
  float acc[8];
  #pragma unroll
  for (int n = 0; n < 8; n++) acc[n] = b[tid];
  for (int k = 0; k < EFD; k++){
    float w = W[k * H + tid];
    #pragma unroll
    for (int n = 0; n < 8; n++) acc[n] += efs[n][k] * w;
  }
  for (int n = 0; n < 8; n++){
    float s1 = acc[n], s2 = acc[n] * acc[n];
    blockReduce2(s1, s2, scr);
    float m = s1 / H, va = s2 / H - m * m;
    float y = (acc[n] - m) * rsqrtf(va + 1e-5f) * g[tid] + be[tid];
    y = fmaxf(y, 0.f);
    eab[(size_t)(e0 + n) * H + tid] = f2bf(y);
  }
}

// ---------------- CSR build: histogram, scan, place ----------------
__global__ void hist_kernel(const int* __restrict__ dst, int* __restrict__ cnt){
  int e = blockIdx.x * 256 + threadIdx.x;
  if (e < NE) atomicAdd(&cnt[dst[e]], 1);
}

// single block of 256 threads, exclusive scan over NN bins
__global__ void scan_kernel(const int* __restrict__ cnt, int* __restrict__ start,
                            int* __restrict__ cursor){
  __shared__ int sums[256];
  int tid = threadIdx.x;
  const int PER = (NN + 255) / 256;   // 40
  int base = tid * PER;
  int s = 0;
  for (int i = 0; i < PER; i++){ int idx = base + i; if (idx < NN) s += cnt[idx]; }
  sums[tid] = s;
  __syncthreads();
  for (int o = 1; o < 256; o <<= 1){
    int t = (tid >= o) ? sums[tid - o] : 0;
    __syncthreads();
    sums[tid] += t;
    __syncthreads();
  }
  int run = sums[tid] - s;   // exclusive prefix of this thread's chunk
  for (int i = 0; i < PER; i++){
    int idx = base + i;
    if (idx < NN){ start[idx] = run; cursor[idx] = run; run += cnt[idx]; }
  }
}

__global__ void place_kernel(const int* __restrict__ dst, int* __restrict__ cursor,
                             int* __restrict__ pos){
  int e = blockIdx.x * 256 + threadIdx.x;
  if (e < NE) pos[e] = atomicAdd(&cursor[dst[e]], 1);
}

// ---------------- weight packing into MFMA fragment order ----------------
// w1p[l][kb(24)][cb(16)][lane(64)][i(8)] = w1[l][kb*32+8*(lane>>4)+i][cb*16+(lane&15)]
__global__ void pack_w1(const float* __restrict__ w1, unsigned short* __restrict__ w1p){
  int b = blockIdx.x;            // l*384 + kb*16 + cb  (3*24*16 = 1152)
  int lane = threadIdx.x;
  int l = b / 384; int rem = b % 384; int kb = rem >> 4; int cb = rem & 15;
  const float* W = w1 + (size_t)l * 768 * H;
  unsigned short* out = w1p + ((size_t)b * 64 + lane) * 8;
  int col = cb * 16 + (lane & 15);
  int k0 = kb * 32 + 8 * (lane >> 4);
  #pragma unroll
  for (int i = 0; i < 8; i++) out[i] = f2bf(W[(size_t)(k0 + i) * H + col]);
}

// w2tp[l][hb(16)][kb(8)][lane(64)][i(8)] = w2[l][kb*32+8*(lane>>4)+i][hb*16+(lane&15)]
__global__ void pack_w2t(const float* __restrict__ w2, unsigned short* __restrict__ w2tp){
  int b = blockIdx.x;            // l*128 + hb*8 + kb  (3*16*8 = 384)
  int lane = threadIdx.x;
  int l = b / 128; int rem = b % 128; int hb = rem >> 3; int kb = rem & 7;
  const float* W = w2 + (size_t)l * H * H;
  unsigned short* out = w2tp + ((size_t)b * 64 + lane) * 8;
  int row = hb * 16 + (lane & 15);   // output col of C2
  int k0 = kb * 32 + 8 * (lane >> 4);
  #pragma unroll
  for (int i = 0; i < 8; i++) out[i] = f2bf(W[(size_t)(k0 + i) * H + row]);
}

// ---------------- fused edge MLP (GEMM1 + relu + GEMM2 + sorted store) --------
// 64 edges / block, 4 waves. GEMM1: C1[64,256] = relu(A[64,768] @ W1 + b1)
// GEMM2: C2^T[256,64] = W2^T @ C1^T ; store (+b2) as bf16 rows at m[pos[e]].
__launch_bounds__(256)
__global__ void edge_mlp(const unsigned short* __restrict__ xb,
                         const unsigned short* __restrict__ eab,
                         const int* __restrict__ src, const int* __restrict__ dst,
                         const int* __restrict__ pos,
                         const unsigned short* __restrict__ w1p,
                         const float* __restrict__ b1,
                         const unsigned short* __restrict__ w2tp,
                         const float* __restrict__ b2,
                         unsigned short* __restrict__ m){
  __shared__ unsigned short As[64 * 64];     // K-tile staging, XOR-swizzled (8 KB)
  __shared__ unsigned short C1s[64 * 256];   // C1 bf16, XOR-swizzled (32 KB)
  __shared__ int srcs[64], dsts[64], poss[64];
  int tid = threadIdx.x;
  int e0 = blockIdx.x * 64;
  if (tid < 64){
    srcs[tid] = src[e0 + tid];
    dsts[tid] = dst[e0 + tid];
    poss[tid] = pos[e0 + tid];
  }
  int wave = tid >> 6, lane = tid & 63;
  int rl = lane & 15, q = lane >> 4;
  v4f acc[4][4];
  #pragma unroll
  for (int i = 0; i < 4; i++)
    #pragma unroll
    for (int j = 0; j < 4; j++) acc[i][j] = (v4f){0.f, 0.f, 0.f, 0.f};

  for (int kt = 0; kt < 12; ++kt){
    int seg = kt >> 2, off = (kt & 3) * 64;
    __syncthreads();
    #pragma unroll
    for (int h = 0; h < 2; ++h){
      int c = tid + h * 256;          // 512 chunks of 16B: edge = c>>3, chunk = c&7
      int e = c >> 3, ck = c & 7;
      const unsigned short* p;
      if (seg == 0)      p = xb + (size_t)srcs[e] * H;
      else if (seg == 1) p = xb + (size_t)dsts[e] * H;
      else               p = eab + (size_t)(e0 + e) * H;
      int4 v = *(const int4*)(p + off + ck * 8);
      *(int4*)&As[e * 64 + ((ck ^ (e & 7)) << 3)] = v;
    }
    __syncthreads();
    #pragma unroll
    for (int k2 = 0; k2 < 2; k2++){
      int kb = kt * 2 + k2;           // global k-block (0..23)
      v8s af[4];
      #pragma unroll
      for (int rb = 0; rb < 4; rb++){
        int row = rb * 16 + rl;
        int ck = k2 * 4 + q;
        af[rb] = *(const v8s*)&As[row * 64 + ((ck ^ (row & 7)) << 3)];
      }
      #pragma unroll
      for (int cb = 0; cb < 4; cb++){
        v8s bf = *(const v8s*)&w1p[(((size_t)kb * 16 + (wave * 4 + cb)) * 64 + lane) * 8];
        #pragma unroll
        for (int rb = 0; rb < 4; rb++)
          acc[rb][cb] = __builtin_amdgcn_mfma_f32_16x16x32_bf16(af[rb], bf, acc[rb][cb], 0, 0, 0);
      }
    }
  }
  // GEMM1 epilogue: bias + relu -> bf16 -> swizzled LDS (row-major [edge][hidden])
  #pragma unroll
  for (int rb = 0; rb < 4; rb++){
    #pragma unroll
    for (int cb = 0; cb < 4; cb++){
      int col = wave * 64 + cb * 16 + rl;
      float bb = b1[col];
      #pragma unroll
      for (int j = 0; j < 4; j++){
        int row = rb * 16 + q * 4 + j;
        float v = fmaxf(acc[rb][cb][j] + bb, 0.f);
        C1s[row * 256 + (((col >> 3) ^ (row & 7)) << 3) + (col & 7)] = f2bf(v);
      }
    }
  }
  __syncthreads();
  // GEMM2: D = W2^T @ C1^T, wave owns output-cols [64w, 64w+64)
  v4f acc2[4][4];
  #pragma unroll
  for (int i = 0; i < 4; i++)
    #pragma unroll
    for (int j = 0; j < 4; j++) acc2[i][j] = (v4f){0.f, 0.f, 0.f, 0.f};
  #pragma unroll
  for (int kb = 0; kb < 8; kb++){
    v8s af[4];
    #pragma unroll
    for (int rb = 0; rb < 4; rb++)
      af[rb] = *(const v8s*)&w2tp[(((size_t)(wave * 4 + rb) * 8 + kb) * 64 + lane) * 8];
    #pragma unroll
    for (int cb = 0; cb < 4; cb++){
      int row = cb * 16 + rl;         // edge row in C1s
      int ck = kb * 4 + q;
      v8s bf = *(const v8s*)&C1s[row * 256 + ((ck ^ (row & 7)) << 3)];
      #pragma unroll
      for (int rb = 0; rb < 4; rb++)
        acc2[rb][cb] = __builtin_amdgcn_mfma_f32_16x16x32_bf16(af[rb], bf, acc2[rb][cb], 0, 0, 0);
    }
  }
  // store: D[row=out-col][col=edge]; row of m = pos[e], bf16, coalesced 8B stores
  #pragma unroll
  for (int cb = 0; cb < 4; cb++){
    int e = cb * 16 + rl;
    unsigned short* mrow = m + (size_t)poss[e] * H;
    #pragma unroll
    for (int rb = 0; rb < 4; rb++){
      int oc0 = wave * 64 + rb * 16 + q * 4;
      ushort4 v;
      v.x = f2bf(acc2[rb][cb][0] + b2[oc0 + 0]);
      v.y = f2bf(acc2[rb][cb][1] + b2[oc0 + 1]);
      v.z = f2bf(acc2[rb][cb][2] + b2[oc0 + 2]);
      v.w = f2bf(acc2[rb][cb][3] + b2[oc0 + 3]);
      *(ushort4*)&mrow[oc0] = v;
    }
  }
}

// ---------------- segment mean: agg[n] = mean(m[start[n]..start[n]+cnt[n]]) ----
// 4 nodes / block, one wave per node, lane owns 4 columns
__global__ void agg_kernel(const unsigned short* __restrict__ m,
                           const int* __restrict__ start, const int* __restrict__ cnt,
                           float* __restrict__ agg){
  int node = blockIdx.x * 4 + (threadIdx.x >> 6);
  int lane = threadIdx.x & 63;
  int s0 = start[node], d = cnt[node];
  float a0 = 0.f, a1 = 0.f, a2 = 0.f, a3 = 0.f;
  const unsigned short* base = m + (size_t)s0 * H + lane * 4;
  for (int r = 0; r < d; r++){
    ushort4 v = *(const ushort4*)(base + (size_t)r * H);
    a0 += bf2f(v.x); a1 += bf2f(v.y); a2 += bf2f(v.z); a3 += bf2f(v.w);
  }
  float inv = 1.f / fmaxf((float)d, 1.f);
  float4 o = {a0 * inv, a1 * inv, a2 * inv, a3 * inv};
  *(float4*)&agg[(size_t)node * H + lane * 4] = o;
}

// ---------------- fused GRU + LayerNorm (8 nodes / block) ----------------
__global__ void gru_kernel(const float* __restrict__ agg, const int* __restrict__ cnt,
                           float* __restrict__ x, unsigned short* __restrict__ xb,
                           const float* __restrict__ wih, const float* __restrict__ whh,
                           const float* __restrict__ bih, const float* __restrict__ bhh,
                           const float* __restrict__ lng, const float* __restrict__ lnb){
  __shared__ float aggs[8][H];
  __shared__ float xs[8][H];
  __shared__ float hs[8][H];
  __shared__ float scr[8];
  __shared__ float dg[8];
  int tid = threadIdx.x;
  int n0 = blockIdx.x * 8;
  if (tid < 8) dg[tid] = (float)cnt[n0 + tid];
  __syncthreads();
  for (int idx = tid; idx < 8 * H; idx += 256){
    int n = idx >> 8, k = idx & 255;
    aggs[n][k] = agg[(size_t)(n0 + n) * H + k];
    xs[n][k]   = x[(size_t)(n0 + n) * H + k];
  }
  __syncthreads();
  float gr[8] = {0}, gz[8] = {0}, gn[8] = {0}, hr[8] = {0}, hz[8] = {0}, hn[8] = {0};
  for (int k = 0; k < H; k++){
    float wr = wih[k * 768 + tid], wz = wih[k * 768 + 256 + tid], wn = wih[k * 768 + 512 + tid];
    float ur = whh[k * 768 + tid], uz = whh[k * 768 + 256 + tid], un = whh[k * 768 + 512 + tid];
    #pragma unroll
    for (int n = 0; n < 8; n++){
      float a = aggs[n][k], xx = xs[n][k];
      gr[n] += a * wr;  gz[n] += a * wz;  gn[n] += a * wn;
      hr[n] += xx * ur; hz[n] += xx * uz; hn[n] += xx * un;
    }
  }
  float bir = bih[tid], biz = bih[256 + tid], bin = bih[512 + tid];
  float bhr = bhh[tid], bhz = bhh[256 + tid], bhn = bhh[512 + tid];
  #pragma unroll
  for (int n = 0; n < 8; n++){
    float r  = 1.f / (1.f + __expf(-(gr[n] + bir + hr[n] + bhr)));
    float z  = 1.f / (1.f + __expf(-(gz[n] + biz + hz[n] + bhz)));
    float ng = tanhf(gn[n] + bin + r * (hn[n] + bhn));
    float hnew = (1.f - z) * ng + z * xs[n][tid];
    hs[n][tid] = (dg[n] > 0.f) ? hnew : xs[n][tid];
  }
  __syncthreads();
  for (int n = 0; n < 8; n++){
    float v0 = hs[n][tid];
    float s1 = v0, s2 = v0 * v0;
    blockReduce2(s1, s2, scr);
    float m = s1 / H, va = s2 / H - m * m;
    float y = (v0 - m) * rsqrtf(va + 1e-5f) * lng[tid] + lnb[tid];
    x[(size_t)(n0 + n) * H + tid] = y;
    xb[(size_t)(n0 + n) * H + tid] = f2bf(y);
  }
}

// ---------------- attention scores ----------------
__global__ void scores_kernel(const float* __restrict__ x, const float* __restrict__ w1,
                              const float* __restrict__ b1, const float* __restrict__ w2,
                              const float* __restrict__ b2, float* __restrict__ s){
  __shared__ float xs[4][H];
  __shared__ float scr[8];
  int tid = threadIdx.x;
  int n0 = blockIdx.x * 4;
  for (int idx = tid; idx < 4 * H; idx += 256){
    int n = idx >> 8, k = idx & 255;
    xs[n][k] = x[(size_t)(n0 + n) * H + k];
  }
  __syncthreads();
  float acc[4];
  #pragma unroll
  for (int n = 0; n < 4; n++) acc[n] = b1[tid];
  for (int k = 0; k < H; k++){
    float w = w1[k * H + tid];
    #pragma unroll
    for (int n = 0; n < 4; n++) acc[n] += xs[n][k] * w;
  }
  float w2v = w2[tid];
  for (int n = 0; n < 4; n++){
    float s1 = tanhf(acc[n]) * w2v, s2 = 0.f;
    blockReduce2(s1, s2, scr);
    if (tid == 0) s[n0 + n] = s1 + b2[0];
  }
}

// ---------------- per-graph softmax pooling (16 blocks) ----------------
__global__ void pool_kernel(const float* __restrict__ x, const float* __restrict__ s,
                            const int* __restrict__ batch, float* __restrict__ pooled){
  __shared__ float scr[8];
  int g = blockIdx.x, tid = threadIdx.x;
  // boundaries in sorted batch
  int a = 0, b = NN;
  while (a < b){ int mid = (a + b) >> 1; if (batch[mid] < g) a = mid + 1; else b = mid; }
  int lo = a;
  a = lo; b = NN;
  while (a < b){ int mid = (a + b) >> 1; if (batch[mid] < g + 1) a = mid + 1; else b = mid; }
  int hi = a;
  // max
  float mx = -3.4e38f;
  for (int i = lo + tid; i < hi; i += 256) mx = fmaxf(mx, s[i]);
  #pragma unroll
  for (int o = 32; o > 0; o >>= 1) mx = fmaxf(mx, __shfl_down(mx, o));
  int lane = tid & 63, w = tid >> 6;
  __syncthreads();
  if (lane == 0) scr[w] = mx;
  __syncthreads();
  mx = fmaxf(fmaxf(scr[0], scr[1]), fmaxf(scr[2], scr[3]));
  // denom
  float den = 0.f;
  for (int i = lo + tid; i < hi; i += 256) den += __expf(s[i] - mx);
  float d2 = 0.f;
  blockReduce2(den, d2, scr);
  // weighted sum; thread owns column tid
  float pj = 0.f;
  for (int i = lo; i < hi; i++){
    float wgt = __expf(s[i] - mx);
    pj += wgt * x[(size_t)i * H + tid];
  }
  pooled[g * H + tid] = pj / den;
}

// ---------------- final projection + LN ----------------
__global__ void proj_kernel(const float* __restrict__ pooled, const float* __restrict__ W,
                            const float* __restrict__ b, const float* __restrict__ g,
                            const float* __restrict__ be, float* __restrict__ out){
  __shared__ float ps[H];
  __shared__ float scr[8];
  int gi = blockIdx.x, tid = threadIdx.x;
  ps[tid] = pooled[gi * H + tid];
  __syncthreads();
  float a0 = b[tid], a1 = b[tid + 256];
  for (int k = 0; k < H; k++){
    float p = ps[k];
    a0 += p * W[k * OUTD + tid];
    a1 += p * W[k * OUTD + tid + 256];
  }
  float s1 = a0 + a1, s2 = a0 * a0 + a1 * a1;
  blockReduce2(s1, s2, scr);
  float m = s1 / OUTD, va = s2 / OUTD - m * m;
  float rs = rsqrtf(va + 1e-5f);
  out[gi * OUTD + tid]       = (a0 - m) * rs * g[tid] + be[tid];
  out[gi * OUTD + tid + 256] = (a1 - m) * rs * g[tid + 256] + be[tid + 256];
}

extern "C" void kernel_launch(void* const* d_in, const int* in_sizes, int n_in,
                              void* d_out, int out_size, void* d_ws, size_t ws_size,
                              hipStream_t stream){
  const float* nf        = (const float*)d_in[0];
  const int*   eidx      = (const int*)d_in[1];
  const float* ef        = (const float*)d_in[2];
  const int*   batch     = (const int*)d_in[3];
  const float* node_w    = (const float*)d_in[4];
  const float* node_b    = (const float*)d_in[5];
  const float* node_g    = (const float*)d_in[6];
  const float* node_beta = (const float*)d_in[7];
  const float* edge_w    = (const float*)d_in[8];
  const float* edge_b    = (const float*)d_in[9];
  const float* edge_g    = (const float*)d_in[10];
  const float* edge_beta = (const float*)d_in[11];
  const float* mp_w1     = (const float*)d_in[12];
  const float* mp_b1     = (const float*)d_in[13];
  const float* mp_w2     = (const float*)d_in[14];
  const float* mp_b2     = (const float*)d_in[15];
  const float* gru_wih   = (const float*)d_in[16];
  const float* gru_whh   = (const float*)d_in[17];
  const float* gru_bih   = (const float*)d_in[18];
  const float* gru_bhh   = (const float*)d_in[19];
  const float* mp_ln_g   = (const float*)d_in[20];
  const float* mp_ln_b   = (const float*)d_in[21];
  const float* att_w1    = (const float*)d_in[22];
  const float* att_b1    = (const float*)d_in[23];
  const float* att_w2    = (const float*)d_in[24];
  const float* att_b2    = (const float*)d_in[25];
  const float* proj_w    = (const float*)d_in[26];
  const float* proj_b    = (const float*)d_in[27];
  const float* proj_g    = (const float*)d_in[28];
  const float* proj_beta = (const float*)d_in[29];
  const int* src = eidx;
  const int* dst = eidx + NE;

  char* ws = (char*)d_ws;
  size_t off = 0;
  auto alloc = [&](size_t bytes) -> void* {
    void* p = ws + off;
    off += (bytes + 511) & ~(size_t)511;
    return p;
  };
  float*          x      = (float*)alloc((size_t)NN * H * 4);
  unsigned short* xb     = (unsigned short*)alloc((size_t)NN * H * 2);
  unsigned short* eab    = (unsigned short*)alloc((size_t)NE * H * 2);
  unsigned short* m      = (unsigned short*)alloc((size_t)NE * H * 2);
  float*          agg    = (float*)alloc((size_t)NN * H * 4);
  int*            cnt    = (int*)alloc((size_t)NN * 4);
  int*            startA = (int*)alloc((size_t)NN * 4);
  int*            cursor = (int*)alloc((size_t)NN * 4);
  int*            pos    = (int*)alloc((size_t)NE * 4);
  float*          s      = (float*)alloc((size_t)NN * 4);
  float*          pooled = (float*)alloc((size_t)NG * H * 4);
  unsigned short* w1p    = (unsigned short*)alloc((size_t)3 * 24 * 16 * 64 * 8 * 2);
  unsigned short* w2tp   = (unsigned short*)alloc((size_t)3 * 16 * 8 * 64 * 8 * 2);

  // CSR build (dst is layer-invariant)
  hipMemsetAsync(cnt, 0, (size_t)NN * 4, stream);
  hist_kernel<<<(NE + 255) / 256, 256, 0, stream>>>(dst, cnt);
  scan_kernel<<<1, 256, 0, stream>>>(cnt, startA, cursor);
  place_kernel<<<(NE + 255) / 256, 256, 0, stream>>>(dst, cursor, pos);

  pack_w1<<<1152, 64, 0, stream>>>(mp_w1, w1p);
  pack_w2t<<<384, 64, 0, stream>>>(mp_w2, w2tp);
  node_enc<<<NN / 4, 256, 0, stream>>>(nf, node_w, node_b, node_g, node_beta, x, xb);
  edge_enc<<<NE / 8, 256, 0, stream>>>(ef, edge_w, edge_b, edge_g, edge_beta, eab);

  for (int l = 0; l < NL; l++){
    edge_mlp<<<NE / 64, 256, 0, stream>>>(xb, eab, src, dst, pos,
        w1p + (size_t)l * 24 * 16 * 64 * 8, mp_b1 + l * H,
        w2tp + (size_t)l * 16 * 8 * 64 * 8, mp_b2 + l * H, m);
    agg_kernel<<<NN / 4, 256, 0, stream>>>(m, startA, cnt, agg);
    gru_kernel<<<NN / 8, 256, 0, stream>>>(agg, cnt, x, xb,
        gru_wih + (size_t)l * H * 768, gru_whh + (size_t)l * H * 768,
        gru_bih + l * 768, gru_bhh + l * 768,
        mp_ln_g + l * H, mp_ln_b + l * H);
  }
  scores_kernel<<<NN / 4, 256, 0, stream>>>(x, att_w1, att_b1, att_w2, att_b2, s);
  pool_kernel<<<NG, 256, 0, stream>>>(x, s, batch, pooled);
  proj_kernel<<<NG, 256, 0, stream>>>(pooled, proj_w, proj_b, proj_g, proj_beta, (float*)d_out);
  (void)in_sizes; (void)n_in; (void)out_size; (void)ws_size;
}

// Round 15
// 1432.334 us; speedup vs baseline: 2.1194x; 1.3399x over previous
//
#include <hip/hip_runtime.h>

#define NN 10000
#define NE 160000
#define NG 16
#define NFD 64
#define EFD 32
#define H 256
#define OUTD 512
#define NL 3

typedef short v8s __attribute__((ext_vector_type(8)));
typedef float v4f __attribute__((ext_vector_type(4)));

__device__ __forceinline__ unsigned short f2bf(float f){
  unsigned int u = __float_as_uint(f);
  u = u + 0x7fffu + ((u >> 16) & 1u);
  return (unsigned short)(u >> 16);
}
__device__ __forceinline__ float bf2f(unsigned short u){
  return __uint_as_float(((unsigned int)u) << 16);
}

// ---------------- node encoder: x = relu(LN(nf @ W + b)) ----------------
// batched LN reduction: 1 sync for staging + 1 sync for partials
__global__ void node_enc(const float* __restrict__ nf, const float* __restrict__ W,
                         const float* __restrict__ b, const float* __restrict__ g,
                         const float* __restrict__ be,
                         float* __restrict__ x, unsigned short* __restrict__ xb){
  __shared__ float nfs[4][NFD];
  __shared__ float scr[16][2];
  int tid = threadIdx.x;
  int n0 = blockIdx.x * 4;
  { int n = tid >> 6, k = tid & 63; nfs[n][k] = nf[(n0 + n) * NFD + k]; }
  __syncthreads();
  float acc[4];
  float bb = b[tid];
  #pragma unroll
  for (int n = 0; n < 4; n++) acc[n] = bb;
  const float4* nfs4 = (const float4*)nfs;   // [4][16]
  for (int kq = 0; kq < 16; kq++){
    float w0 = W[(kq * 4 + 0) * H + tid];
    float w1 = W[(kq * 4 + 1) * H + tid];
    float w2 = W[(kq * 4 + 2) * H + tid];
    float w3 = W[(kq * 4 + 3) * H + tid];
    #pragma unroll
    for (int n = 0; n < 4; n++){
      float4 e4 = nfs4[n * 16 + kq];
      acc[n] += e4.x * w0 + e4.y * w1 + e4.z * w2 + e4.w * w3;
    }
  }
  int lane = tid & 63, w = tid >> 6;
  float s1[4], s2[4];
  #pragma unroll
  for (int n = 0; n < 4; n++){
    s1[n] = acc[n]; s2[n] = acc[n] * acc[n];
    #pragma unroll
    for (int o = 32; o > 0; o >>= 1){
      s1[n] += __shfl_down(s1[n], o);
      s2[n] += __shfl_down(s2[n], o);
    }
  }
  if (lane == 0){
    #pragma unroll
    for (int n = 0; n < 4; n++){ scr[w * 4 + n][0] = s1[n]; scr[w * 4 + n][1] = s2[n]; }
  }
  __syncthreads();
  float gg = g[tid], bbe = be[tid];
  #pragma unroll
  for (int n = 0; n < 4; n++){
    float S1 = scr[n][0] + scr[4 + n][0] + scr[8 + n][0] + scr[12 + n][0];
    float S2 = scr[n][1] + scr[4 + n][1] + scr[8 + n][1] + scr[12 + n][1];
    float m = S1 / H, va = S2 / H - m * m;
    float y = (acc[n] - m) * rsqrtf(va + 1e-5f) * gg + bbe;
    y = fmaxf(y, 0.f);
    x[(size_t)(n0 + n) * H + tid] = y;
    xb[(size_t)(n0 + n) * H + tid] = f2bf(y);
  }
}

// ---------------- edge encoder: edge_attr = relu(LN(ef @ W + b)) (bf16) ------
__global__ void edge_enc(const float* __restrict__ ef, const float* __restrict__ W,
                         const float* __restrict__ b, const float* __restrict__ g,
                         const float* __restrict__ be, unsigned short* __restrict__ eab){
  __shared__ float efs[8][EFD];
  __shared__ float scr[32][2];
  int tid = threadIdx.x;
  int e0 = blockIdx.x * 8;
  { int n = tid >> 5, k = tid & 31; efs[n][k] = ef[(e0 + n) * EFD + k]; }
  __syncthreads();
  float acc[8];
  float bb = b[tid];
  #pragma unroll
  for (int n = 0; n < 8; n++) acc[n] = bb;
  const float4* efs4 = (const float4*)efs;   // [8][8]
  for (int kq = 0; kq < 8; kq++){
    float w0 = W[(kq * 4 + 0) * H + tid];
    float w1 = W[(kq * 4 + 1) * H + tid];
    float w2 = W[(kq * 4 + 2) * H + tid];
    float w3 = W[(kq * 4 + 3) * H + tid];
    #pragma unroll
    for (int n = 0; n < 8; n++){
      float4 e4 = efs4[n * 8 + kq];
      acc[n] += e4.x * w0 + e4.y * w1 + e4.z * w2 + e4.w * w3;
    }
  }
  int lane = tid & 63, w = tid >> 6;
  float s1[8], s2[8];
  #pragma unroll
  for (int n = 0; n < 8; n++){
    s1[n] = acc[n]; s2[n] = acc[n] * acc[n];
    #pragma unroll
    for (int o = 32; o > 0; o >>= 1){
      s1[n] += __shfl_down(s1[n], o);
      s2[n] += __shfl_down(s2[n], o);
    }
  }
  if (lane == 0){
    #pragma unroll
    for (int n = 0; n < 8; n++){ scr[w * 8 + n][0] = s1[n]; scr[w * 8 + n][1] = s2[n]; }
  }
  __syncthreads();
  float gg = g[tid], bbe = be[tid];
  #pragma unroll
  for (int n = 0; n < 8; n++){
    float S1 = scr[n][0] + scr[8 + n][0] + scr[16 + n][0] + scr[24 + n][0];
    float S2 = scr[n][1] + scr[8 + n][1] + scr[16 + n][1] + scr[24 + n][1];
    float m = S1 / H, va = S2 / H - m * m;
    float y = (acc[n] - m) * rsqrtf(va + 1e-5f) * gg + bbe;
    y = fmaxf(y, 0.f);
    eab[(size_t)(e0 + n) * H + tid] = f2bf(y);
  }
}

// ---------------- CSR build: histogram, scan, place ----------------
__global__ void hist_kernel(const int* __restrict__ dst, int* __restrict__ cnt){
  int e = blockIdx.x * 256 + threadIdx.x;
  if (e < NE) atomicAdd(&cnt[dst[e]], 1);
}

__global__ void scan_kernel(const int* __restrict__ cnt, int* __restrict__ start,
                            int* __restrict__ cursor){
  __shared__ int sums[256];
  int tid = threadIdx.x;
  const int PER = (NN + 255) / 256;   // 40
  int base = tid * PER;
  int s = 0;
  for (int i = 0; i < PER; i++){ int idx = base + i; if (idx < NN) s += cnt[idx]; }
  sums[tid] = s;
  __syncthreads();
  for (int o = 1; o < 256; o <<= 1){
    int t = (tid >= o) ? sums[tid - o] : 0;
    __syncthreads();
    sums[tid] += t;
    __syncthreads();
  }
  int run = sums[tid] - s;   // exclusive prefix of this thread's chunk
  for (int i = 0; i < PER; i++){
    int idx = base + i;
    if (idx < NN){ start[idx] = run; cursor[idx] = run; run += cnt[idx]; }
  }
}

__global__ void place_kernel(const int* __restrict__ dst, int* __restrict__ cursor,
                             int* __restrict__ pos){
  int e = blockIdx.x * 256 + threadIdx.x;
  if (e < NE) pos[e] = atomicAdd(&cursor[dst[e]], 1);
}

// ---------------- weight packing into MFMA fragment order ----------------
__global__ void pack_w1(const float* __restrict__ w1, unsigned short* __restrict__ w1p){
  int b = blockIdx.x;            // l*384 + kb*16 + cb
  int lane = threadIdx.x;
  int l = b / 384; int rem = b % 384; int kb = rem >> 4; int cb = rem & 15;
  const float* W = w1 + (size_t)l * 768 * H;
  unsigned short* out = w1p + ((size_t)b * 64 + lane) * 8;
  int col = cb * 16 + (lane & 15);
  int k0 = kb * 32 + 8 * (lane >> 4);
  #pragma unroll
  for (int i = 0; i < 8; i++) out[i] = f2bf(W[(size_t)(k0 + i) * H + col]);
}

__global__ void pack_w2t(const float* __restrict__ w2, unsigned short* __restrict__ w2tp){
  int b = blockIdx.x;            // l*128 + hb*8 + kb
  int lane = threadIdx.x;
  int l = b / 128; int rem = b % 128; int hb = rem >> 3; int kb = rem & 7;
  const float* W = w2 + (size_t)l * H * H;
  unsigned short* out = w2tp + ((size_t)b * 64 + lane) * 8;
  int row = hb * 16 + (lane & 15);
  int k0 = kb * 32 + 8 * (lane >> 4);
  #pragma unroll
  for (int i = 0; i < 8; i++) out[i] = f2bf(W[(size_t)(k0 + i) * H + row]);
}

// GRU combined weight W''(512x1024): cols [r_sum|z_sum|gi_n|gh_n]
// W''[r][c] = r<256 ? (c<768 ? wih[r][c] : 0)
//                   : (c<512 ? whh[r-256][c] : (c>=768 ? whh[r-256][c-256] : 0))
__global__ void pack_gruw(const float* __restrict__ wih, const float* __restrict__ whh,
                          unsigned short* __restrict__ gruw){
  int b = blockIdx.x;            // l*1024 + kb*64 + cb  (3*16*64 = 3072)
  int lane = threadIdx.x;
  int l = b >> 10; int rem = b & 1023; int kb = rem >> 6; int cb = rem & 63;
  const float* WI = wih + (size_t)l * H * 768;
  const float* WH = whh + (size_t)l * H * 768;
  unsigned short* out = gruw + ((size_t)b * 64 + lane) * 8;
  int c = cb * 16 + (lane & 15);
  int r0 = kb * 32 + 8 * (lane >> 4);
  #pragma unroll
  for (int i = 0; i < 8; i++){
    int r = r0 + i;
    float v;
    if (r < 256) v = (c < 768) ? WI[(size_t)r * 768 + c] : 0.f;
    else         v = (c < 512) ? WH[(size_t)(r - 256) * 768 + c]
                               : ((c >= 768) ? WH[(size_t)(r - 256) * 768 + (c - 256)] : 0.f);
    out[i] = f2bf(v);
  }
}

// ---------------- fused edge MLP (GEMM1 + relu + GEMM2 + sorted store) -------
__launch_bounds__(256)
__global__ void edge_mlp(const unsigned short* __restrict__ xb,
                         const unsigned short* __restrict__ eab,
                         const int* __restrict__ src, const int* __restrict__ dst,
                         const int* __restrict__ pos,
                         const unsigned short* __restrict__ w1p,
                         const float* __restrict__ b1,
                         const unsigned short* __restrict__ w2tp,
                         const float* __restrict__ b2,
                         unsigned short* __restrict__ m){
  __shared__ unsigned short As[64 * 64];
  __shared__ unsigned short C1s[64 * 256];
  __shared__ int srcs[64], dsts[64], poss[64];
  int tid = threadIdx.x;
  int e0 = blockIdx.x * 64;
  if (tid < 64){
    srcs[tid] = src[e0 + tid];
    dsts[tid] = dst[e0 + tid];
    poss[tid] = pos[e0 + tid];
  }
  int wave = tid >> 6, lane = tid & 63;
  int rl = lane & 15, q = lane >> 4;
  v4f acc[4][4];
  #pragma unroll
  for (int i = 0; i < 4; i++)
    #pragma unroll
    for (int j = 0; j < 4; j++) acc[i][j] = (v4f){0.f, 0.f, 0.f, 0.f};

  for (int kt = 0; kt < 12; ++kt){
    int seg = kt >> 2, off = (kt & 3) * 64;
    __syncthreads();
    #pragma unroll
    for (int h = 0; h < 2; ++h){
      int c = tid + h * 256;
      int e = c >> 3, ck = c & 7;
      const unsigned short* p;
      if (seg == 0)      p = xb + (size_t)srcs[e] * H;
      else if (seg == 1) p = xb + (size_t)dsts[e] * H;
      else               p = eab + (size_t)(e0 + e) * H;
      int4 v = *(const int4*)(p + off + ck * 8);
      *(int4*)&As[e * 64 + ((ck ^ (e & 7)) << 3)] = v;
    }
    __syncthreads();
    #pragma unroll
    for (int k2 = 0; k2 < 2; k2++){
      int kb = kt * 2 + k2;
      v8s af[4];
      #pragma unroll
      for (int rb = 0; rb < 4; rb++){
        int row = rb * 16 + rl;
        int ck = k2 * 4 + q;
        af[rb] = *(const v8s*)&As[row * 64 + ((ck ^ (row & 7)) << 3)];
      }
      #pragma unroll
      for (int cb = 0; cb < 4; cb++){
        v8s bf = *(const v8s*)&w1p[(((size_t)kb * 16 + (wave * 4 + cb)) * 64 + lane) * 8];
        #pragma unroll
        for (int rb = 0; rb < 4; rb++)
          acc[rb][cb] = __builtin_amdgcn_mfma_f32_16x16x32_bf16(af[rb], bf, acc[rb][cb], 0, 0, 0);
      }
    }
  }
  #pragma unroll
  for (int rb = 0; rb < 4; rb++){
    #pragma unroll
    for (int cb = 0; cb < 4; cb++){
      int col = wave * 64 + cb * 16 + rl;
      float bb = b1[col];
      #pragma unroll
      for (int j = 0; j < 4; j++){
        int row = rb * 16 + q * 4 + j;
        float v = fmaxf(acc[rb][cb][j] + bb, 0.f);
        C1s[row * 256 + (((col >> 3) ^ (row & 7)) << 3) + (col & 7)] = f2bf(v);
      }
    }
  }
  __syncthreads();
  v4f acc2[4][4];
  #pragma unroll
  for (int i = 0; i < 4; i++)
    #pragma unroll
    for (int j = 0; j < 4; j++) acc2[i][j] = (v4f){0.f, 0.f, 0.f, 0.f};
  #pragma unroll
  for (int kb = 0; kb < 8; kb++){
    v8s af[4];
    #pragma unroll
    for (int rb = 0; rb < 4; rb++)
      af[rb] = *(const v8s*)&w2tp[(((size_t)(wave * 4 + rb) * 8 + kb) * 64 + lane) * 8];
    #pragma unroll
    for (int cb = 0; cb < 4; cb++){
      int row = cb * 16 + rl;
      int ck = kb * 4 + q;
      v8s bf = *(const v8s*)&C1s[row * 256 + ((ck ^ (row & 7)) << 3)];
      #pragma unroll
      for (int rb = 0; rb < 4; rb++)
        acc2[rb][cb] = __builtin_amdgcn_mfma_f32_16x16x32_bf16(af[rb], bf, acc2[rb][cb], 0, 0, 0);
    }
  }
  #pragma unroll
  for (int cb = 0; cb < 4; cb++){
    int e = cb * 16 + rl;
    unsigned short* mrow = m + (size_t)poss[e] * H;
    #pragma unroll
    for (int rb = 0; rb < 4; rb++){
      int oc0 = wave * 64 + rb * 16 + q * 4;
      ushort4 v;
      v.x = f2bf(acc2[rb][cb][0] + b2[oc0 + 0]);
      v.y = f2bf(acc2[rb][cb][1] + b2[oc0 + 1]);
      v.z = f2bf(acc2[rb][cb][2] + b2[oc0 + 2]);
      v.w = f2bf(acc2[rb][cb][3] + b2[oc0 + 3]);
      *(ushort4*)&mrow[oc0] = v;
    }
  }
}

// ---------------- segment mean -> bf16 agg ----------------
__global__ void agg_kernel(const unsigned short* __restrict__ m,
                           const int* __restrict__ start, const int* __restrict__ cnt,
                           unsigned short* __restrict__ aggb){
  int node = blockIdx.x * 4 + (threadIdx.x >> 6);
  int lane = threadIdx.x & 63;
  int s0 = start[node], d = cnt[node];
  float a0 = 0.f, a1 = 0.f, a2 = 0.f, a3 = 0.f;
  const unsigned short* base = m + (size_t)s0 * H + lane * 4;
  for (int r = 0; r < d; r++){
    ushort4 v = *(const ushort4*)(base + (size_t)r * H);
    a0 += bf2f(v.x); a1 += bf2f(v.y); a2 += bf2f(v.z); a3 += bf2f(v.w);
  }
  float inv = 1.f / fmaxf((float)d, 1.f);
  ushort4 o;
  o.x = f2bf(a0 * inv); o.y = f2bf(a1 * inv); o.z = f2bf(a2 * inv); o.w = f2bf(a3 * inv);
  *(ushort4*)&aggb[(size_t)node * H + lane * 4] = o;
}

// ---------------- GRU gates GEMM: [aggb|xb](10000x512) @ W''(512x1024) -------
// 32 nodes/block, 8 waves; wave owns 128 output cols.
__launch_bounds__(512)
__global__ void gates_gemm(const unsigned short* __restrict__ aggb,
                           const unsigned short* __restrict__ xb,
                           const unsigned short* __restrict__ gruw,
                           float* __restrict__ gates){
  __shared__ unsigned short As[32 * 64];
  int tid = threadIdx.x;
  int n0 = blockIdx.x * 32;
  int wave = tid >> 6, lane = tid & 63;
  int rl = lane & 15, q = lane >> 4;
  v4f acc[2][8];
  #pragma unroll
  for (int i = 0; i < 2; i++)
    #pragma unroll
    for (int j = 0; j < 8; j++) acc[i][j] = (v4f){0.f, 0.f, 0.f, 0.f};

  for (int kt = 0; kt < 8; kt++){
    __syncthreads();
    if (tid < 256){
      int e = tid >> 3, ck = tid & 7;
      int n = n0 + e; if (n >= NN) n = NN - 1;
      const unsigned short* p = (kt < 4) ? (aggb + (size_t)n * H + kt * 64)
                                         : (xb   + (size_t)n * H + (kt - 4) * 64);
      int4 v = *(const int4*)(p + ck * 8);
      *(int4*)&As[e * 64 + ((ck ^ (e & 7)) << 3)] = v;
    }
    __syncthreads();
    #pragma unroll
    for (int ks = 0; ks < 2; ks++){
      int kb = kt * 2 + ks;
      v8s af[2];
      #pragma unroll
      for (int rb = 0; rb < 2; rb++){
        int row = rb * 16 + rl;
        int ck = ks * 4 + q;
        af[rb] = *(const v8s*)&As[row * 64 + ((ck ^ (row & 7)) << 3)];
      }
      #pragma unroll
      for (int cb = 0; cb < 8; cb++){
        v8s bf = *(const v8s*)&gruw[(((size_t)kb * 64 + (wave * 8 + cb)) * 64 + lane) * 8];
        #pragma unroll
        for (int rb = 0; rb < 2; rb++)
          acc[rb][cb] = __builtin_amdgcn_mfma_f32_16x16x32_bf16(af[rb], bf, acc[rb][cb], 0, 0, 0);
      }
    }
  }
  #pragma unroll
  for (int rb = 0; rb < 2; rb++){
    #pragma unroll
    for (int cb = 0; cb < 8; cb++){
      int col = wave * 128 + cb * 16 + rl;
      #pragma unroll
      for (int j = 0; j < 4; j++){
        int row = n0 + rb * 16 + q * 4 + j;
        if (row < NN) gates[(size_t)row * 1024 + col] = acc[rb][cb][j];
      }
    }
  }
}

// ---------------- GRU elementwise + LayerNorm (4 nodes/block) ----------------
__global__ void gru_elem(const float* __restrict__ gates, const int* __restrict__ cnt,
                         float* __restrict__ x, unsigned short* __restrict__ xb,
                         const float* __restrict__ bih, const float* __restrict__ bhh,
                         const float* __restrict__ lng, const float* __restrict__ lnb){
  __shared__ float scr[16][2];
  __shared__ float dgs[4];
  int tid = threadIdx.x;
  int n0 = blockIdx.x * 4;
  if (tid < 4) dgs[tid] = (float)cnt[n0 + tid];
  __syncthreads();
  float bir = bih[tid], biz = bih[256 + tid], bin = bih[512 + tid];
  float bhr = bhh[tid], bhz = bhh[256 + tid], bhn = bhh[512 + tid];
  float h[4];
  #pragma unroll
  for (int n = 0; n < 4; n++){
    const float* gp = gates + (size_t)(n0 + n) * 1024;
    float rs = gp[tid], zs = gp[256 + tid], gin = gp[512 + tid], ghn = gp[768 + tid];
    float xv = x[(size_t)(n0 + n) * H + tid];
    float r  = 1.f / (1.f + __expf(-(rs + bir + bhr)));
    float z  = 1.f / (1.f + __expf(-(zs + biz + bhz)));
    float ng = tanhf(gin + bin + r * (ghn + bhn));
    float hn = (1.f - z) * ng + z * xv;
    h[n] = (dgs[n] > 0.f) ? hn : xv;
  }
  int lane = tid & 63, w = tid >> 6;
  float s1[4], s2[4];
  #pragma unroll
  for (int n = 0; n < 4; n++){
    s1[n] = h[n]; s2[n] = h[n] * h[n];
    #pragma unroll
    for (int o = 32; o > 0; o >>= 1){
      s1[n] += __shfl_down(s1[n], o);
      s2[n] += __shfl_down(s2[n], o);
    }
  }
  if (lane == 0){
    #pragma unroll
    for (int n = 0; n < 4; n++){ scr[w * 4 + n][0] = s1[n]; scr[w * 4 + n][1] = s2[n]; }
  }
  __syncthreads();
  float gg = lng[tid], bb = lnb[tid];
  #pragma unroll
  for (int n = 0; n < 4; n++){
    float S1 = scr[n][0] + scr[4 + n][0] + scr[8 + n][0] + scr[12 + n][0];
    float S2 = scr[n][1] + scr[4 + n][1] + scr[8 + n][1] + scr[12 + n][1];
    float m = S1 / H, va = S2 / H - m * m;
    float y = (h[n] - m) * rsqrtf(va + 1e-5f) * gg + bb;
    x[(size_t)(n0 + n) * H + tid] = y;
    xb[(size_t)(n0 + n) * H + tid] = f2bf(y);
  }
}

// ---------------- attention scores ----------------
__global__ void scores_kernel(const float* __restrict__ x, const float* __restrict__ w1,
                              const float* __restrict__ b1, const float* __restrict__ w2,
                              const float* __restrict__ b2, float* __restrict__ s){
  __shared__ float xs[4][H];
  __shared__ float scr[16];
  int tid = threadIdx.x;
  int n0 = blockIdx.x * 4;
  for (int idx = tid; idx < 4 * H; idx += 256){
    int n = idx >> 8, k = idx & 255;
    xs[n][k] = x[(size_t)(n0 + n) * H + k];
  }
  __syncthreads();
  float acc[4];
  float bb = b1[tid];
  #pragma unroll
  for (int n = 0; n < 4; n++) acc[n] = bb;
  const float4* xs4 = (const float4*)xs;   // [4][64]
  for (int kq = 0; kq < 64; kq++){
    float w0 = w1[(kq * 4 + 0) * H + tid];
    float w1v = w1[(kq * 4 + 1) * H + tid];
    float w2v = w1[(kq * 4 + 2) * H + tid];
    float w3 = w1[(kq * 4 + 3) * H + tid];
    #pragma unroll
    for (int n = 0; n < 4; n++){
      float4 e4 = xs4[n * 64 + kq];
      acc[n] += e4.x * w0 + e4.y * w1v + e4.z * w2v + e4.w * w3;
    }
  }
  float wv = w2[tid];
  int lane = tid & 63, w = tid >> 6;
  float t[4];
  #pragma unroll
  for (int n = 0; n < 4; n++){
    t[n] = tanhf(acc[n]) * wv;
    #pragma unroll
    for (int o = 32; o > 0; o >>= 1) t[n] += __shfl_down(t[n], o);
  }
  if (lane == 0){
    #pragma unroll
    for (int n = 0; n < 4; n++) scr[w * 4 + n] = t[n];
  }
  __syncthreads();
  if (tid < 4) s[n0 + tid] = scr[tid] + scr[4 + tid] + scr[8 + tid] + scr[12 + tid] + b2[0];
}

// ---------------- per-graph softmax pooling (16 blocks) ----------------
__global__ void pool_kernel(const float* __restrict__ x, const float* __restrict__ s,
                            const int* __restrict__ batch, float* __restrict__ pooled){
  __shared__ float scr[8];
  int g = blockIdx.x, tid = threadIdx.x;
  int a = 0, b = NN;
  while (a < b){ int mid = (a + b) >> 1; if (batch[mid] < g) a = mid + 1; else b = mid; }
  int lo = a;
  a = lo; b = NN;
  while (a < b){ int mid = (a + b) >> 1; if (batch[mid] < g + 1) a = mid + 1; else b = mid; }
  int hi = a;
  float mx = -3.4e38f;
  for (int i = lo + tid; i < hi; i += 256) mx = fmaxf(mx, s[i]);
  #pragma unroll
  for (int o = 32; o > 0; o >>= 1) mx = fmaxf(mx, __shfl_down(mx, o));
  int lane = tid & 63, w = tid >> 6;
  __syncthreads();
  if (lane == 0) scr[w] = mx;
  __syncthreads();
  mx = fmaxf(fmaxf(scr[0], scr[1]), fmaxf(scr[2], scr[3]));
  float den = 0.f;
  for (int i = lo + tid; i < hi; i += 256) den += __expf(s[i] - mx);
  #pragma unroll
  for (int o = 32; o > 0; o >>= 1) den += __shfl_down(den, o);
  __syncthreads();
  if (lane == 0) scr[4 + w] = den;
  __syncthreads();
  den = scr[4] + scr[5] + scr[6] + scr[7];
  float pj = 0.f;
  for (int i = lo; i < hi; i++){
    float wgt = __expf(s[i] - mx);
    pj += wgt * x[(size_t)i * H + tid];
  }
  pooled[g * H + tid] = pj / den;
}

// ---------------- final projection + LN ----------------
__global__ void proj_kernel(const float* __restrict__ pooled, const float* __restrict__ W,
                            const float* __restrict__ b, const float* __restrict__ g,
                            const float* __restrict__ be, float* __restrict__ out){
  __shared__ float ps[H];
  __shared__ float scr[8];
  int gi = blockIdx.x, tid = threadIdx.x;
  ps[tid] = pooled[gi * H + tid];
  __syncthreads();
  float a0 = b[tid], a1 = b[tid + 256];
  for (int k = 0; k < H; k++){
    float p = ps[k];
    a0 += p * W[k * OUTD + tid];
    a1 += p * W[k * OUTD + tid + 256];
  }
  float s1 = a0 + a1, s2 = a0 * a0 + a1 * a1;
  int lane = tid & 63, w = tid >> 6;
  #pragma unroll
  for (int o = 32; o > 0; o >>= 1){
    s1 += __shfl_down(s1, o);
    s2 += __shfl_down(s2, o);
  }
  __syncthreads();
  if (lane == 0){ scr[w] = s1; scr[4 + w] = s2; }
  __syncthreads();
  s1 = scr[0] + scr[1] + scr[2] + scr[3];
  s2 = scr[4] + scr[5] + scr[6] + scr[7];
  float m = s1 / OUTD, va = s2 / OUTD - m * m;
  float rs = rsqrtf(va + 1e-5f);
  out[gi * OUTD + tid]       = (a0 - m) * rs * g[tid] + be[tid];
  out[gi * OUTD + tid + 256] = (a1 - m) * rs * g[tid + 256] + be[tid + 256];
}

extern "C" void kernel_launch(void* const* d_in, const int* in_sizes, int n_in,
                              void* d_out, int out_size, void* d_ws, size_t ws_size,
                              hipStream_t stream){
  const float* nf        = (const float*)d_in[0];
  const int*   eidx      = (const int*)d_in[1];
  const float* ef        = (const float*)d_in[2];
  const int*   batch     = (const int*)d_in[3];
  const float* node_w    = (const float*)d_in[4];
  const float* node_b    = (const float*)d_in[5];
  const float* node_g    = (const float*)d_in[6];
  const float* node_beta = (const float*)d_in[7];
  const float* edge_w    = (const float*)d_in[8];
  const float* edge_b    = (const float*)d_in[9];
  const float* edge_g    = (const float*)d_in[10];
  const float* edge_beta = (const float*)d_in[11];
  const float* mp_w1     = (const float*)d_in[12];
  const float* mp_b1     = (const float*)d_in[13];
  const float* mp_w2     = (const float*)d_in[14];
  const float* mp_b2     = (const float*)d_in[15];
  const float* gru_wih   = (const float*)d_in[16];
  const float* gru_whh   = (const float*)d_in[17];
  const float* gru_bih   = (const float*)d_in[18];
  const float* gru_bhh   = (const float*)d_in[19];
  const float* mp_ln_g   = (const float*)d_in[20];
  const float* mp_ln_b   = (const float*)d_in[21];
  const float* att_w1    = (const float*)d_in[22];
  const float* att_b1    = (const float*)d_in[23];
  const float* att_w2    = (const float*)d_in[24];
  const float* att_b2    = (const float*)d_in[25];
  const float* proj_w    = (const float*)d_in[26];
  const float* proj_b    = (const float*)d_in[27];
  const float* proj_g    = (const float*)d_in[28];
  const float* proj_beta = (const float*)d_in[29];
  const int* src = eidx;
  const int* dst = eidx + NE;

  char* ws = (char*)d_ws;
  size_t off = 0;
  auto alloc = [&](size_t bytes) -> void* {
    void* p = ws + off;
    off += (bytes + 511) & ~(size_t)511;
    return p;
  };
  float*          x      = (float*)alloc((size_t)NN * H * 4);
  unsigned short* xb     = (unsigned short*)alloc((size_t)NN * H * 2);
  unsigned short* eab    = (unsigned short*)alloc((size_t)NE * H * 2);
  unsigned short* m      = (unsigned short*)alloc((size_t)NE * H * 2);
  unsigned short* aggb   = (unsigned short*)alloc((size_t)NN * H * 2);
  int*            cnt    = (int*)alloc((size_t)NN * 4);
  int*            startA = (int*)alloc((size_t)NN * 4);
  int*            cursor = (int*)alloc((size_t)NN * 4);
  int*            pos    = (int*)alloc((size_t)NE * 4);
  float*          s      = (float*)alloc((size_t)NN * 4);
  float*          pooled = (float*)alloc((size_t)NG * H * 4);
  unsigned short* w1p    = (unsigned short*)alloc((size_t)3 * 24 * 16 * 64 * 8 * 2);
  unsigned short* w2tp   = (unsigned short*)alloc((size_t)3 * 16 * 8 * 64 * 8 * 2);
  unsigned short* gruw   = (unsigned short*)alloc((size_t)3 * 16 * 64 * 64 * 8 * 2);
  // gates (NN x 1024 fp32 = 41 MB) aliases m (82 MB): m is dead after agg_kernel,
  // rewritten by next layer's edge_mlp after gates are consumed by gru_elem.
  float*          gates  = (float*)m;

  // CSR build (dst is layer-invariant)
  hipMemsetAsync(cnt, 0, (size_t)NN * 4, stream);
  hist_kernel<<<(NE + 255) / 256, 256, 0, stream>>>(dst, cnt);
  scan_kernel<<<1, 256, 0, stream>>>(cnt, startA, cursor);
  place_kernel<<<(NE + 255) / 256, 256, 0, stream>>>(dst, cursor, pos);

  pack_w1<<<1152, 64, 0, stream>>>(mp_w1, w1p);
  pack_w2t<<<384, 64, 0, stream>>>(mp_w2, w2tp);
  pack_gruw<<<3072, 64, 0, stream>>>(gru_wih, gru_whh, gruw);
  node_enc<<<NN / 4, 256, 0, stream>>>(nf, node_w, node_b, node_g, node_beta, x, xb);
  edge_enc<<<NE / 8, 256, 0, stream>>>(ef, edge_w, edge_b, edge_g, edge_beta, eab);

  for (int l = 0; l < NL; l++){
    edge_mlp<<<NE / 64, 256, 0, stream>>>(xb, eab, src, dst, pos,
        w1p + (size_t)l * 24 * 16 * 64 * 8, mp_b1 + l * H,
        w2tp + (size_t)l * 16 * 8 * 64 * 8, mp_b2 + l * H, m);
    agg_kernel<<<NN / 4, 256, 0, stream>>>(m, startA, cnt, aggb);
    gates_gemm<<<(NN + 31) / 32, 512, 0, stream>>>(aggb, xb,
        gruw + (size_t)l * 16 * 64 * 64 * 8, gates);
    gru_elem<<<NN / 4, 256, 0, stream>>>(gates, cnt, x, xb,
        gru_bih + l * 768, gru_bhh + l * 768,
        mp_ln_g + l * H, mp_ln_b + l * H);
  }
  scores_kernel<<<NN / 4, 256, 0, stream>>>(x, att_w1, att_b1, att_w2, att_b2, s);
  pool_kernel<<<NG, 256, 0, stream>>>(x, s, batch, pooled);
  proj_kernel<<<NG, 256, 0, stream>>>(pooled, proj_w, proj_b, proj_g, proj_beta, (float*)d_out);
  (void)in_sizes; (void)n_in; (void)out_size; (void)ws_size;
}

// Round 16
// 1320.711 us; speedup vs baseline: 2.2985x; 1.0845x over previous
//
#include <hip/hip_runtime.h>

#define NN 10000
#define NE 160000
#define NG 16
#define NFD 64
#define EFD 32
#define H 256
#define OUTD 512
#define NL 3

typedef short v8s __attribute__((ext_vector_type(8)));
typedef float v4f __attribute__((ext_vector_type(4)));

__device__ __forceinline__ unsigned short f2bf(float f){
  unsigned int u = __float_as_uint(f);
  u = u + 0x7fffu + ((u >> 16) & 1u);
  return (unsigned short)(u >> 16);
}
__device__ __forceinline__ float bf2f(unsigned short u){
  return __uint_as_float(((unsigned int)u) << 16);
}

// ---------------- node encoder: x = relu(LN(nf @ W + b)) ----------------
__global__ void node_enc(const float* __restrict__ nf, const float* __restrict__ W,
                         const float* __restrict__ b, const float* __restrict__ g,
                         const float* __restrict__ be,
                         float* __restrict__ x, unsigned short* __restrict__ xb){
  __shared__ float nfs[4][NFD];
  __shared__ float scr[16][2];
  int tid = threadIdx.x;
  int n0 = blockIdx.x * 4;
  { int n = tid >> 6, k = tid & 63; nfs[n][k] = nf[(n0 + n) * NFD + k]; }
  __syncthreads();
  float acc[4];
  float bb = b[tid];
  #pragma unroll
  for (int n = 0; n < 4; n++) acc[n] = bb;
  const float4* nfs4 = (const float4*)nfs;   // [4][16]
  for (int kq = 0; kq < 16; kq++){
    float w0 = W[(kq * 4 + 0) * H + tid];
    float w1 = W[(kq * 4 + 1) * H + tid];
    float w2 = W[(kq * 4 + 2) * H + tid];
    float w3 = W[(kq * 4 + 3) * H + tid];
    #pragma unroll
    for (int n = 0; n < 4; n++){
      float4 e4 = nfs4[n * 16 + kq];
      acc[n] += e4.x * w0 + e4.y * w1 + e4.z * w2 + e4.w * w3;
    }
  }
  int lane = tid & 63, w = tid >> 6;
  float s1[4], s2[4];
  #pragma unroll
  for (int n = 0; n < 4; n++){
    s1[n] = acc[n]; s2[n] = acc[n] * acc[n];
    #pragma unroll
    for (int o = 32; o > 0; o >>= 1){
      s1[n] += __shfl_down(s1[n], o);
      s2[n] += __shfl_down(s2[n], o);
    }
  }
  if (lane == 0){
    #pragma unroll
    for (int n = 0; n < 4; n++){ scr[w * 4 + n][0] = s1[n]; scr[w * 4 + n][1] = s2[n]; }
  }
  __syncthreads();
  float gg = g[tid], bbe = be[tid];
  #pragma unroll
  for (int n = 0; n < 4; n++){
    float S1 = scr[n][0] + scr[4 + n][0] + scr[8 + n][0] + scr[12 + n][0];
    float S2 = scr[n][1] + scr[4 + n][1] + scr[8 + n][1] + scr[12 + n][1];
    float m = S1 / H, va = S2 / H - m * m;
    float y = (acc[n] - m) * rsqrtf(va + 1e-5f) * gg + bbe;
    y = fmaxf(y, 0.f);
    x[(size_t)(n0 + n) * H + tid] = y;
    xb[(size_t)(n0 + n) * H + tid] = f2bf(y);
  }
}

// ---------------- edge encoder: edge_attr = relu(LN(ef @ W + b)) (bf16) ------
__global__ void edge_enc(const float* __restrict__ ef, const float* __restrict__ W,
                         const float* __restrict__ b, const float* __restrict__ g,
                         const float* __restrict__ be, unsigned short* __restrict__ eab){
  __shared__ float efs[8][EFD];
  __shared__ float scr[32][2];
  int tid = threadIdx.x;
  int e0 = blockIdx.x * 8;
  { int n = tid >> 5, k = tid & 31; efs[n][k] = ef[(e0 + n) * EFD + k]; }
  __syncthreads();
  float acc[8];
  float bb = b[tid];
  #pragma unroll
  for (int n = 0; n < 8; n++) acc[n] = bb;
  const float4* efs4 = (const float4*)efs;   // [8][8]
  for (int kq = 0; kq < 8; kq++){
    float w0 = W[(kq * 4 + 0) * H + tid];
    float w1 = W[(kq * 4 + 1) * H + tid];
    float w2 = W[(kq * 4 + 2) * H + tid];
    float w3 = W[(kq * 4 + 3) * H + tid];
    #pragma unroll
    for (int n = 0; n < 8; n++){
      float4 e4 = efs4[n * 8 + kq];
      acc[n] += e4.x * w0 + e4.y * w1 + e4.z * w2 + e4.w * w3;
    }
  }
  int lane = tid & 63, w = tid >> 6;
  float s1[8], s2[8];
  #pragma unroll
  for (int n = 0; n < 8; n++){
    s1[n] = acc[n]; s2[n] = acc[n] * acc[n];
    #pragma unroll
    for (int o = 32; o > 0; o >>= 1){
      s1[n] += __shfl_down(s1[n], o);
      s2[n] += __shfl_down(s2[n], o);
    }
  }
  if (lane == 0){
    #pragma unroll
    for (int n = 0; n < 8; n++){ scr[w * 8 + n][0] = s1[n]; scr[w * 8 + n][1] = s2[n]; }
  }
  __syncthreads();
  float gg = g[tid], bbe = be[tid];
  #pragma unroll
  for (int n = 0; n < 8; n++){
    float S1 = scr[n][0] + scr[8 + n][0] + scr[16 + n][0] + scr[24 + n][0];
    float S2 = scr[n][1] + scr[8 + n][1] + scr[16 + n][1] + scr[24 + n][1];
    float m = S1 / H, va = S2 / H - m * m;
    float y = (acc[n] - m) * rsqrtf(va + 1e-5f) * gg + bbe;
    y = fmaxf(y, 0.f);
    eab[(size_t)(e0 + n) * H + tid] = f2bf(y);
  }
}

// ---------------- CSR build: histogram, scan, place ----------------
__global__ void hist_kernel(const int* __restrict__ dst, int* __restrict__ cnt){
  int e = blockIdx.x * 256 + threadIdx.x;
  if (e < NE) atomicAdd(&cnt[dst[e]], 1);
}

__global__ void scan_kernel(const int* __restrict__ cnt, int* __restrict__ start,
                            int* __restrict__ cursor){
  __shared__ int sums[256];
  int tid = threadIdx.x;
  const int PER = (NN + 255) / 256;   // 40
  int base = tid * PER;
  int s = 0;
  for (int i = 0; i < PER; i++){ int idx = base + i; if (idx < NN) s += cnt[idx]; }
  sums[tid] = s;
  __syncthreads();
  for (int o = 1; o < 256; o <<= 1){
    int t = (tid >= o) ? sums[tid - o] : 0;
    __syncthreads();
    sums[tid] += t;
    __syncthreads();
  }
  int run = sums[tid] - s;   // exclusive prefix of this thread's chunk
  for (int i = 0; i < PER; i++){
    int idx = base + i;
    if (idx < NN){ start[idx] = run; cursor[idx] = run; run += cnt[idx]; }
  }
}

__global__ void place_kernel(const int* __restrict__ dst, int* __restrict__ cursor,
                             int* __restrict__ pos){
  int e = blockIdx.x * 256 + threadIdx.x;
  if (e < NE) pos[e] = atomicAdd(&cursor[dst[e]], 1);
}

// ---------------- weight packing into MFMA fragment order ----------------
__global__ void pack_w1(const float* __restrict__ w1, unsigned short* __restrict__ w1p){
  int b = blockIdx.x;            // l*384 + kb*16 + cb
  int lane = threadIdx.x;
  int l = b / 384; int rem = b % 384; int kb = rem >> 4; int cb = rem & 15;
  const float* W = w1 + (size_t)l * 768 * H;
  unsigned short* out = w1p + ((size_t)b * 64 + lane) * 8;
  int col = cb * 16 + (lane & 15);
  int k0 = kb * 32 + 8 * (lane >> 4);
  #pragma unroll
  for (int i = 0; i < 8; i++) out[i] = f2bf(W[(size_t)(k0 + i) * H + col]);
}

__global__ void pack_w2t(const float* __restrict__ w2, unsigned short* __restrict__ w2tp){
  int b = blockIdx.x;            // l*128 + hb*8 + kb
  int lane = threadIdx.x;
  int l = b / 128; int rem = b % 128; int hb = rem >> 3; int kb = rem & 7;
  const float* W = w2 + (size_t)l * H * H;
  unsigned short* out = w2tp + ((size_t)b * 64 + lane) * 8;
  int row = hb * 16 + (lane & 15);
  int k0 = kb * 32 + 8 * (lane >> 4);
  #pragma unroll
  for (int i = 0; i < 8; i++) out[i] = f2bf(W[(size_t)(k0 + i) * H + row]);
}

// GRU combined weight W''(512x1024): cols [r_sum|z_sum|gi_n|gh_n]
__global__ void pack_gruw(const float* __restrict__ wih, const float* __restrict__ whh,
                          unsigned short* __restrict__ gruw){
  int b = blockIdx.x;            // l*1024 + kb*64 + cb  (3*16*64 = 3072)
  int lane = threadIdx.x;
  int l = b >> 10; int rem = b & 1023; int kb = rem >> 6; int cb = rem & 63;
  const float* WI = wih + (size_t)l * H * 768;
  const float* WH = whh + (size_t)l * H * 768;
  unsigned short* out = gruw + ((size_t)b * 64 + lane) * 8;
  int c = cb * 16 + (lane & 15);
  int r0 = kb * 32 + 8 * (lane >> 4);
  #pragma unroll
  for (int i = 0; i < 8; i++){
    int r = r0 + i;
    float v;
    if (r < 256) v = (c < 768) ? WI[(size_t)r * 768 + c] : 0.f;
    else         v = (c < 512) ? WH[(size_t)(r - 256) * 768 + c]
                               : ((c >= 768) ? WH[(size_t)(r - 256) * 768 + (c - 256)] : 0.f);
    out[i] = f2bf(v);
  }
}

// ---------------- fused edge MLP (pipelined GEMM1 + relu + GEMM2 + store) ----
// 64 edges/block, 4 waves. Double-buffered register-prefetch staging:
// one barrier per K-tile; gathers for kt+1 fly under kt's MFMAs.
__launch_bounds__(256)
__global__ void edge_mlp(const unsigned short* __restrict__ xb,
                         const unsigned short* __restrict__ eab,
                         const int* __restrict__ src, const int* __restrict__ dst,
                         const int* __restrict__ pos,
                         const unsigned short* __restrict__ w1p,
                         const float* __restrict__ b1,
                         const unsigned short* __restrict__ w2tp,
                         const float* __restrict__ b2,
                         unsigned short* __restrict__ m){
  __shared__ unsigned short As[2][64 * 64];   // double-buffered K-tile (16 KB)
  __shared__ unsigned short C1s[64 * 256];    // C1 bf16, swizzled (32 KB)
  __shared__ int srcs[64], dsts[64], poss[64];
  int tid = threadIdx.x;
  int e0 = blockIdx.x * 64;
  if (tid < 64){
    srcs[tid] = src[e0 + tid];
    dsts[tid] = dst[e0 + tid];
    poss[tid] = pos[e0 + tid];
  }
  int wave = tid >> 6, lane = tid & 63;
  int rl = lane & 15, q = lane >> 4;
  // staging geometry: thread covers chunks c=tid and c=tid+256; edge=c>>3, ck=c&7
  int eA = tid >> 3, eB = 32 + eA, ckk = tid & 7;
  int swA = eA * 64 + ((ckk ^ (eA & 7)) << 3);
  int swB = eB * 64 + ((ckk ^ (eB & 7)) << 3);
  __syncthreads();   // srcs/dsts/poss visible

  int4 r0, r1;
  { // prologue: kt=0 (seg 0, off 0)
    const unsigned short* p0 = xb + (size_t)srcs[eA] * H;
    const unsigned short* p1 = xb + (size_t)srcs[eB] * H;
    r0 = *(const int4*)(p0 + ckk * 8);
    r1 = *(const int4*)(p1 + ckk * 8);
  }

  v4f acc[4][4];
  #pragma unroll
  for (int i = 0; i < 4; i++)
    #pragma unroll
    for (int j = 0; j < 4; j++) acc[i][j] = (v4f){0.f, 0.f, 0.f, 0.f};

  for (int kt = 0; kt < 12; ++kt){
    unsigned short* Ab = As[kt & 1];
    *(int4*)&Ab[swA] = r0;
    *(int4*)&Ab[swB] = r1;
    __syncthreads();
    if (kt < 11){
      int kn = kt + 1;
      int seg = kn >> 2, off = (kn & 3) * 64;
      const unsigned short *p0, *p1;
      if (seg == 0){      p0 = xb + (size_t)srcs[eA] * H; p1 = xb + (size_t)srcs[eB] * H; }
      else if (seg == 1){ p0 = xb + (size_t)dsts[eA] * H; p1 = xb + (size_t)dsts[eB] * H; }
      else {              p0 = eab + (size_t)(e0 + eA) * H; p1 = eab + (size_t)(e0 + eB) * H; }
      r0 = *(const int4*)(p0 + off + ckk * 8);
      r1 = *(const int4*)(p1 + off + ckk * 8);
    }
    #pragma unroll
    for (int k2 = 0; k2 < 2; k2++){
      int kb = kt * 2 + k2;
      v8s af[4];
      #pragma unroll
      for (int rb = 0; rb < 4; rb++){
        int row = rb * 16 + rl;
        int ck = k2 * 4 + q;
        af[rb] = *(const v8s*)&Ab[row * 64 + ((ck ^ (row & 7)) << 3)];
      }
      #pragma unroll
      for (int cb = 0; cb < 4; cb++){
        v8s bf = *(const v8s*)&w1p[(((size_t)kb * 16 + (wave * 4 + cb)) * 64 + lane) * 8];
        #pragma unroll
        for (int rb = 0; rb < 4; rb++)
          acc[rb][cb] = __builtin_amdgcn_mfma_f32_16x16x32_bf16(af[rb], bf, acc[rb][cb], 0, 0, 0);
      }
    }
  }
  // GEMM1 epilogue: bias + relu -> bf16 -> swizzled LDS
  #pragma unroll
  for (int rb = 0; rb < 4; rb++){
    #pragma unroll
    for (int cb = 0; cb < 4; cb++){
      int col = wave * 64 + cb * 16 + rl;
      float bb = b1[col];
      #pragma unroll
      for (int j = 0; j < 4; j++){
        int row = rb * 16 + q * 4 + j;
        float v = fmaxf(acc[rb][cb][j] + bb, 0.f);
        C1s[row * 256 + (((col >> 3) ^ (row & 7)) << 3) + (col & 7)] = f2bf(v);
      }
    }
  }
  __syncthreads();
  // GEMM2: D = W2^T @ C1^T, wave owns output-cols [64w, 64w+64)
  v4f acc2[4][4];
  #pragma unroll
  for (int i = 0; i < 4; i++)
    #pragma unroll
    for (int j = 0; j < 4; j++) acc2[i][j] = (v4f){0.f, 0.f, 0.f, 0.f};
  #pragma unroll
  for (int kb = 0; kb < 8; kb++){
    v8s af[4];
    #pragma unroll
    for (int rb = 0; rb < 4; rb++)
      af[rb] = *(const v8s*)&w2tp[(((size_t)(wave * 4 + rb) * 8 + kb) * 64 + lane) * 8];
    #pragma unroll
    for (int cb = 0; cb < 4; cb++){
      int row = cb * 16 + rl;
      int ck = kb * 4 + q;
      v8s bf = *(const v8s*)&C1s[row * 256 + ((ck ^ (row & 7)) << 3)];
      #pragma unroll
      for (int rb = 0; rb < 4; rb++)
        acc2[rb][cb] = __builtin_amdgcn_mfma_f32_16x16x32_bf16(af[rb], bf, acc2[rb][cb], 0, 0, 0);
    }
  }
  // store: row of m = pos[e], bf16, coalesced 8B stores
  #pragma unroll
  for (int cb = 0; cb < 4; cb++){
    int e = cb * 16 + rl;
    unsigned short* mrow = m + (size_t)poss[e] * H;
    #pragma unroll
    for (int rb = 0; rb < 4; rb++){
      int oc0 = wave * 64 + rb * 16 + q * 4;
      ushort4 v;
      v.x = f2bf(acc2[rb][cb][0] + b2[oc0 + 0]);
      v.y = f2bf(acc2[rb][cb][1] + b2[oc0 + 1]);
      v.z = f2bf(acc2[rb][cb][2] + b2[oc0 + 2]);
      v.w = f2bf(acc2[rb][cb][3] + b2[oc0 + 3]);
      *(ushort4*)&mrow[oc0] = v;
    }
  }
}

// ---------------- segment mean -> bf16 agg ----------------
__global__ void agg_kernel(const unsigned short* __restrict__ m,
                           const int* __restrict__ start, const int* __restrict__ cnt,
                           unsigned short* __restrict__ aggb){
  int node = blockIdx.x * 4 + (threadIdx.x >> 6);
  int lane = threadIdx.x & 63;
  int s0 = start[node], d = cnt[node];
  float a0 = 0.f, a1 = 0.f, a2 = 0.f, a3 = 0.f;
  const unsigned short* base = m + (size_t)s0 * H + lane * 4;
  for (int r = 0; r < d; r++){
    ushort4 v = *(const ushort4*)(base + (size_t)r * H);
    a0 += bf2f(v.x); a1 += bf2f(v.y); a2 += bf2f(v.z); a3 += bf2f(v.w);
  }
  float inv = 1.f / fmaxf((float)d, 1.f);
  ushort4 o;
  o.x = f2bf(a0 * inv); o.y = f2bf(a1 * inv); o.z = f2bf(a2 * inv); o.w = f2bf(a3 * inv);
  *(ushort4*)&aggb[(size_t)node * H + lane * 4] = o;
}

// ---------------- GRU gates GEMM: [aggb|xb](10000x512) @ W''(512x1024) -------
__launch_bounds__(512)
__global__ void gates_gemm(const unsigned short* __restrict__ aggb,
                           const unsigned short* __restrict__ xb,
                           const unsigned short* __restrict__ gruw,
                           float* __restrict__ gates){
  __shared__ unsigned short As[32 * 64];
  int tid = threadIdx.x;
  int n0 = blockIdx.x * 32;
  int wave = tid >> 6, lane = tid & 63;
  int rl = lane & 15, q = lane >> 4;
  v4f acc[2][8];
  #pragma unroll
  for (int i = 0; i < 2; i++)
    #pragma unroll
    for (int j = 0; j < 8; j++) acc[i][j] = (v4f){0.f, 0.f, 0.f, 0.f};

  for (int kt = 0; kt < 8; kt++){
    __syncthreads();
    if (tid < 256){
      int e = tid >> 3, ck = tid & 7;
      int n = n0 + e; if (n >= NN) n = NN - 1;
      const unsigned short* p = (kt < 4) ? (aggb + (size_t)n * H + kt * 64)
                                         : (xb   + (size_t)n * H + (kt - 4) * 64);
      int4 v = *(const int4*)(p + ck * 8);
      *(int4*)&As[e * 64 + ((ck ^ (e & 7)) << 3)] = v;
    }
    __syncthreads();
    #pragma unroll
    for (int ks = 0; ks < 2; ks++){
      int kb = kt * 2 + ks;
      v8s af[2];
      #pragma unroll
      for (int rb = 0; rb < 2; rb++){
        int row = rb * 16 + rl;
        int ck = ks * 4 + q;
        af[rb] = *(const v8s*)&As[row * 64 + ((ck ^ (row & 7)) << 3)];
      }
      #pragma unroll
      for (int cb = 0; cb < 8; cb++){
        v8s bf = *(const v8s*)&gruw[(((size_t)kb * 64 + (wave * 8 + cb)) * 64 + lane) * 8];
        #pragma unroll
        for (int rb = 0; rb < 2; rb++)
          acc[rb][cb] = __builtin_amdgcn_mfma_f32_16x16x32_bf16(af[rb], bf, acc[rb][cb], 0, 0, 0);
      }
    }
  }
  #pragma unroll
  for (int rb = 0; rb < 2; rb++){
    #pragma unroll
    for (int cb = 0; cb < 8; cb++){
      int col = wave * 128 + cb * 16 + rl;
      #pragma unroll
      for (int j = 0; j < 4; j++){
        int row = n0 + rb * 16 + q * 4 + j;
        if (row < NN) gates[(size_t)row * 1024 + col] = acc[rb][cb][j];
      }
    }
  }
}

// ---------------- GRU elementwise + LayerNorm (4 nodes/block) ----------------
__global__ void gru_elem(const float* __restrict__ gates, const int* __restrict__ cnt,
                         float* __restrict__ x, unsigned short* __restrict__ xb,
                         const float* __restrict__ bih, const float* __restrict__ bhh,
                         const float* __restrict__ lng, const float* __restrict__ lnb){
  __shared__ float scr[16][2];
  __shared__ float dgs[4];
  int tid = threadIdx.x;
  int n0 = blockIdx.x * 4;
  if (tid < 4) dgs[tid] = (float)cnt[n0 + tid];
  __syncthreads();
  float bir = bih[tid], biz = bih[256 + tid], bin = bih[512 + tid];
  float bhr = bhh[tid], bhz = bhh[256 + tid], bhn = bhh[512 + tid];
  float h[4];
  #pragma unroll
  for (int n = 0; n < 4; n++){
    const float* gp = gates + (size_t)(n0 + n) * 1024;
    float rs = gp[tid], zs = gp[256 + tid], gin = gp[512 + tid], ghn = gp[768 + tid];
    float xv = x[(size_t)(n0 + n) * H + tid];
    float r  = 1.f / (1.f + __expf(-(rs + bir + bhr)));
    float z  = 1.f / (1.f + __expf(-(zs + biz + bhz)));
    float ng = tanhf(gin + bin + r * (ghn + bhn));
    float hn = (1.f - z) * ng + z * xv;
    h[n] = (dgs[n] > 0.f) ? hn : xv;
  }
  int lane = tid & 63, w = tid >> 6;
  float s1[4], s2[4];
  #pragma unroll
  for (int n = 0; n < 4; n++){
    s1[n] = h[n]; s2[n] = h[n] * h[n];
    #pragma unroll
    for (int o = 32; o > 0; o >>= 1){
      s1[n] += __shfl_down(s1[n], o);
      s2[n] += __shfl_down(s2[n], o);
    }
  }
  if (lane == 0){
    #pragma unroll
    for (int n = 0; n < 4; n++){ scr[w * 4 + n][0] = s1[n]; scr[w * 4 + n][1] = s2[n]; }
  }
  __syncthreads();
  float gg = lng[tid], bb = lnb[tid];
  #pragma unroll
  for (int n = 0; n < 4; n++){
    float S1 = scr[n][0] + scr[4 + n][0] + scr[8 + n][0] + scr[12 + n][0];
    float S2 = scr[n][1] + scr[4 + n][1] + scr[8 + n][1] + scr[12 + n][1];
    float m = S1 / H, va = S2 / H - m * m;
    float y = (h[n] - m) * rsqrtf(va + 1e-5f) * gg + bb;
    x[(size_t)(n0 + n) * H + tid] = y;
    xb[(size_t)(n0 + n) * H + tid] = f2bf(y);
  }
}

// ---------------- attention scores ----------------
__global__ void scores_kernel(const float* __restrict__ x, const float* __restrict__ w1,
                              const float* __restrict__ b1, const float* __restrict__ w2,
                              const float* __restrict__ b2, float* __restrict__ s){
  __shared__ float xs[4][H];
  __shared__ float scr[16];
  int tid = threadIdx.x;
  int n0 = blockIdx.x * 4;
  for (int idx = tid; idx < 4 * H; idx += 256){
    int n = idx >> 8, k = idx & 255;
    xs[n][k] = x[(size_t)(n0 + n) * H + k];
  }
  __syncthreads();
  float acc[4];
  float bb = b1[tid];
  #pragma unroll
  for (int n = 0; n < 4; n++) acc[n] = bb;
  const float4* xs4 = (const float4*)xs;   // [4][64]
  for (int kq = 0; kq < 64; kq++){
    float w0 = w1[(kq * 4 + 0) * H + tid];
    float w1v = w1[(kq * 4 + 1) * H + tid];
    float w2v = w1[(kq * 4 + 2) * H + tid];
    float w3 = w1[(kq * 4 + 3) * H + tid];
    #pragma unroll
    for (int n = 0; n < 4; n++){
      float4 e4 = xs4[n * 64 + kq];
      acc[n] += e4.x * w0 + e4.y * w1v + e4.z * w2v + e4.w * w3;
    }
  }
  float wv = w2[tid];
  int lane = tid & 63, w = tid >> 6;
  float t[4];
  #pragma unroll
  for (int n = 0; n < 4; n++){
    t[n] = tanhf(acc[n]) * wv;
    #pragma unroll
    for (int o = 32; o > 0; o >>= 1) t[n] += __shfl_down(t[n], o);
  }
  if (lane == 0){
    #pragma unroll
    for (int n = 0; n < 4; n++) scr[w * 4 + n] = t[n];
  }
  __syncthreads();
  if (tid < 4) s[n0 + tid] = scr[tid] + scr[4 + tid] + scr[8 + tid] + scr[12 + tid] + b2[0];
}

// ---------------- per-graph softmax pooling (16 blocks) ----------------
__global__ void pool_kernel(const float* __restrict__ x, const float* __restrict__ s,
                            const int* __restrict__ batch, float* __restrict__ pooled){
  __shared__ float scr[8];
  int g = blockIdx.x, tid = threadIdx.x;
  int a = 0, b = NN;
  while (a < b){ int mid = (a + b) >> 1; if (batch[mid] < g) a = mid + 1; else b = mid; }
  int lo = a;
  a = lo; b = NN;
  while (a < b){ int mid = (a + b) >> 1; if (batch[mid] < g + 1) a = mid + 1; else b = mid; }
  int hi = a;
  float mx = -3.4e38f;
  for (int i = lo + tid; i < hi; i += 256) mx = fmaxf(mx, s[i]);
  #pragma unroll
  for (int o = 32; o > 0; o >>= 1) mx = fmaxf(mx, __shfl_down(mx, o));
  int lane = tid & 63, w = tid >> 6;
  __syncthreads();
  if (lane == 0) scr[w] = mx;
  __syncthreads();
  mx = fmaxf(fmaxf(scr[0], scr[1]), fmaxf(scr[2], scr[3]));
  float den = 0.f;
  for (int i = lo + tid; i < hi; i += 256) den += __expf(s[i] - mx);
  #pragma unroll
  for (int o = 32; o > 0; o >>= 1) den += __shfl_down(den, o);
  __syncthreads();
  if (lane == 0) scr[4 + w] = den;
  __syncthreads();
  den = scr[4] + scr[5] + scr[6] + scr[7];
  float pj = 0.f;
  for (int i = lo; i < hi; i++){
    float wgt = __expf(s[i] - mx);
    pj += wgt * x[(size_t)i * H + tid];
  }
  pooled[g * H + tid] = pj / den;
}

// ---------------- final projection + LN ----------------
__global__ void proj_kernel(const float* __restrict__ pooled, const float* __restrict__ W,
                            const float* __restrict__ b, const float* __restrict__ g,
                            const float* __restrict__ be, float* __restrict__ out){
  __shared__ float ps[H];
  __shared__ float scr[8];
  int gi = blockIdx.x, tid = threadIdx.x;
  ps[tid] = pooled[gi * H + tid];
  __syncthreads();
  float a0 = b[tid], a1 = b[tid + 256];
  for (int k = 0; k < H; k++){
    float p = ps[k];
    a0 += p * W[k * OUTD + tid];
    a1 += p * W[k * OUTD + tid + 256];
  }
  float s1 = a0 + a1, s2 = a0 * a0 + a1 * a1;
  int lane = tid & 63, w = tid >> 6;
  #pragma unroll
  for (int o = 32; o > 0; o >>= 1){
    s1 += __shfl_down(s1, o);
    s2 += __shfl_down(s2, o);
  }
  __syncthreads();
  if (lane == 0){ scr[w] = s1; scr[4 + w] = s2; }
  __syncthreads();
  s1 = scr[0] + scr[1] + scr[2] + scr[3];
  s2 = scr[4] + scr[5] + scr[6] + scr[7];
  float m = s1 / OUTD, va = s2 / OUTD - m * m;
  float rs = rsqrtf(va + 1e-5f);
  out[gi * OUTD + tid]       = (a0 - m) * rs * g[tid] + be[tid];
  out[gi * OUTD + tid + 256] = (a1 - m) * rs * g[tid + 256] + be[tid + 256];
}

extern "C" void kernel_launch(void* const* d_in, const int* in_sizes, int n_in,
                              void* d_out, int out_size, void* d_ws, size_t ws_size,
                              hipStream_t stream){
  const float* nf        = (const float*)d_in[0];
  const int*   eidx      = (const int*)d_in[1];
  const float* ef        = (const float*)d_in[2];
  const int*   batch     = (const int*)d_in[3];
  const float* node_w    = (const float*)d_in[4];
  const float* node_b    = (const float*)d_in[5];
  const float* node_g    = (const float*)d_in[6];
  const float* node_beta = (const float*)d_in[7];
  const float* edge_w    = (const float*)d_in[8];
  const float* edge_b    = (const float*)d_in[9];
  const float* edge_g    = (const float*)d_in[10];
  const float* edge_beta = (const float*)d_in[11];
  const float* mp_w1     = (const float*)d_in[12];
  const float* mp_b1     = (const float*)d_in[13];
  const float* mp_w2     = (const float*)d_in[14];
  const float* mp_b2     = (const float*)d_in[15];
  const float* gru_wih   = (const float*)d_in[16];
  const float* gru_whh   = (const float*)d_in[17];
  const float* gru_bih   = (const float*)d_in[18];
  const float* gru_bhh   = (const float*)d_in[19];
  const float* mp_ln_g   = (const float*)d_in[20];
  const float* mp_ln_b   = (const float*)d_in[21];
  const float* att_w1    = (const float*)d_in[22];
  const float* att_b1    = (const float*)d_in[23];
  const float* att_w2    = (const float*)d_in[24];
  const float* att_b2    = (const float*)d_in[25];
  const float* proj_w    = (const float*)d_in[26];
  const float* proj_b    = (const float*)d_in[27];
  const float* proj_g    = (const float*)d_in[28];
  const float* proj_beta = (const float*)d_in[29];
  const int* src = eidx;
  const int* dst = eidx + NE;

  char* ws = (char*)d_ws;
  size_t off = 0;
  auto alloc = [&](size_t bytes) -> void* {
    void* p = ws + off;
    off += (bytes + 511) & ~(size_t)511;
    return p;
  };
  float*          x      = (float*)alloc((size_t)NN * H * 4);
  unsigned short* xb     = (unsigned short*)alloc((size_t)NN * H * 2);
  unsigned short* eab    = (unsigned short*)alloc((size_t)NE * H * 2);
  unsigned short* m      = (unsigned short*)alloc((size_t)NE * H * 2);
  unsigned short* aggb   = (unsigned short*)alloc((size_t)NN * H * 2);
  int*            cnt    = (int*)alloc((size_t)NN * 4);
  int*            startA = (int*)alloc((size_t)NN * 4);
  int*            cursor = (int*)alloc((size_t)NN * 4);
  int*            pos    = (int*)alloc((size_t)NE * 4);
  float*          s      = (float*)alloc((size_t)NN * 4);
  float*          pooled = (float*)alloc((size_t)NG * H * 4);
  unsigned short* w1p    = (unsigned short*)alloc((size_t)3 * 24 * 16 * 64 * 8 * 2);
  unsigned short* w2tp   = (unsigned short*)alloc((size_t)3 * 16 * 8 * 64 * 8 * 2);
  unsigned short* gruw   = (unsigned short*)alloc((size_t)3 * 16 * 64 * 64 * 8 * 2);
  // gates (NN x 1024 fp32 = 41 MB) aliases m (82 MB): m is dead after agg_kernel,
  // rewritten by next layer's edge_mlp after gates are consumed by gru_elem.
  float*          gates  = (float*)m;

  // CSR build (dst is layer-invariant)
  hipMemsetAsync(cnt, 0, (size_t)NN * 4, stream);
  hist_kernel<<<(NE + 255) / 256, 256, 0, stream>>>(dst, cnt);
  scan_kernel<<<1, 256, 0, stream>>>(cnt, startA, cursor);
  place_kernel<<<(NE + 255) / 256, 256, 0, stream>>>(dst, cursor, pos);

  pack_w1<<<1152, 64, 0, stream>>>(mp_w1, w1p);
  pack_w2t<<<384, 64, 0, stream>>>(mp_w2, w2tp);
  pack_gruw<<<3072, 64, 0, stream>>>(gru_wih, gru_whh, gruw);
  node_enc<<<NN / 4, 256, 0, stream>>>(nf, node_w, node_b, node_g, node_beta, x, xb);
  edge_enc<<<NE / 8, 256, 0, stream>>>(ef, edge_w, edge_b, edge_g, edge_beta, eab);

  for (int l = 0; l < NL; l++){
    edge_mlp<<<NE / 64, 256, 0, stream>>>(xb, eab, src, dst, pos,
        w1p + (size_t)l * 24 * 16 * 64 * 8, mp_b1 + l * H,
        w2tp + (size_t)l * 16 * 8 * 64 * 8, mp_b2 + l * H, m);
    agg_kernel<<<NN / 4, 256, 0, stream>>>(m, startA, cnt, aggb);
    gates_gemm<<<(NN + 31) / 32, 512, 0, stream>>>(aggb, xb,
        gruw + (size_t)l * 16 * 64 * 64 * 8, gates);
    gru_elem<<<NN / 4, 256, 0, stream>>>(gates, cnt, x, xb,
        gru_bih + l * 768, gru_bhh + l * 768,
        mp_ln_g + l * H, mp_ln_b + l * H);
  }
  scores_kernel<<<NN / 4, 256, 0, stream>>>(x, att_w1, att_b1, att_w2, att_b2, s);
  pool_kernel<<<NG, 256, 0, stream>>>(x, s, batch, pooled);
  proj_kernel<<<NG, 256, 0, stream>>>(pooled, proj_w, proj_b, proj_g, proj_beta, (float*)d_out);
  (void)in_sizes; (void)n_in; (void)out_size; (void)ws_size;
}